// Round 2
// baseline (1012.340 us; speedup 1.0000x reference)
//
#include <hip/hip_runtime.h>
#include <hip/hip_fp16.h>
#include <cmath>
#include <cstdint>

// Problem constants (fixed by the reference).
constexpr int P  = 2000, M = 150, DG = 2000, F = 256, H = 4, DH = 64;
constexpr int N1 = P + M;          // 2150
constexpr int N2 = P + DG;         // 4000
constexpr int E1 = 137600, E2 = 256000, EGP = 64000, EGM = 4800;
constexpr int SA_HID = 128;

// Edge-range offsets for the fused build phase.
constexpr int HO1 = E1, HO2 = E1 + E2, HO3 = HO2 + EGP, HO4 = HO3 + EGP,
              HO5 = HO4 + EGM, HOE = HO5 + EGM;   // 531200 total edges

// ELL capacities (overflow list guarantees correctness regardless).
constexpr int CAP_A = 160;
constexpr int CAP_G = 96;
constexpr int OVF_CAP = 4096;

// One counter per 64B line (R7: removed same-line atomic serialization).
constexpr int CPAD = 16;

// ---- fp16 helpers -----------------------------------------------------------
__device__ __forceinline__ float4 h4_to_f4(const __half* p) {
  union { ushort4 u4; __half2 h2[2]; } u;
  u.u4 = *(const ushort4*)p;
  float2 lo = __half22float2(u.h2[0]);
  float2 hi = __half22float2(u.h2[1]);
  return make_float4(lo.x, lo.y, hi.x, hi.y);
}
__device__ __forceinline__ void f4_to_h4(__half* p, float4 v) {
  union { ushort4 u4; __half2 h2[2]; } u;
  u.h2[0] = __float22half2_rn(make_float2(v.x, v.y));
  u.h2[1] = __float22half2_rn(make_float2(v.z, v.w));
  *(ushort4*)p = u.u4;
}

constexpr int CAST_CH = (P * F + M * F + DG * F) / 8;   // 8-float chunks

constexpr int FR  = 8;
constexpr int NB0 = (P + FR - 1) / FR;   // 250
constexpr int NB2 = (M + FR - 1) / FR;   // 19
constexpr int FEAT_BLOCKS = 2 * NB0 + 2 * NB2;

constexpr int SR  = 4;
constexpr int SB0 = (P + SR - 1) / SR;   // 500
constexpr int SB2 = (M + SR - 1) / SR;   // 38
constexpr int SEM_BLOCKS = 2 * SB0 + 2 * SB2;   // 1076 (even)

constexpr int FIN_R = 4;   // P % FIN_R == 0

// ===========================================================================
// Mega-kernel argument block
// ===========================================================================
struct MegaArgs {
  const int* a1r; const int* a1c; const float* a1v;
  const int* a2r; const int* a2c; const float* a2v;
  const int* g0s; const int* g0d; const int* g1s; const int* g1d;
  const int* g2s; const int* g2d; const int* g3s; const int* g3d;
  const float* pE; const float* mE; const float* dE;
  const float* gat_W; const float* gat_al; const float* gat_ar; const float* gat_b;
  const float* sa_W1; const float* sa_b1; const float* sa_W2;
  const float* out_W; const float* out_b;
  int* bcnt; int* bgen;            // custom grid barrier state (zeroed by host)
  int* cur1; int* cur2; int* cu0; int* cu1; int* cu2; int* cu3;
  int* ovf_n; float* wbuf; float* svg;
  int4* ovf; uint2* ell1; uint2* ell2;
  unsigned* eg0; unsigned* eg1; unsigned* eg2; unsigned* eg3;
  __half* pEh; __half* mEh; __half* dEh;
  __half* lat1h; __half* lat2h;
  __half* f0; __half* f1; __half* f2; __half* f3;
  float* lat1f; float* lat2f; float* acc1; float* acc2;
  float* el; float* er;
  float* e0; float* e1; float* e2; float* e3;
  float* out_simi; float* out_dgcn; float* out_med; float* out_mgcn; float* out_pat;
};

// ---------------------------------------------------------------------------
// Custom grid barrier (replaces cg::grid.sync(), which measured ~100+ us/sync
// in R1: VALUBusy 5.5% on a 1175 us dispatch = ~65 us real work).
// Design: arrivals spread over 64 counter lines (bid&63, 64B apart) so RMW
// serialization is ~nb/64 per line; leader block's 64 lanes each poll their
// own line for its exact quota; single gen flip released with agent scope;
// spinners poll gen read-only with s_sleep backoff.
// Requires gridDim.x % 64 == 0 (guaranteed: grid = nbk*256).
// ---------------------------------------------------------------------------
__device__ __forceinline__ void gbarrier(int* cnt, int* gen, int nb, int bid, int tid) {
  __syncthreads();
  if (bid == 0) {
    if (tid < 64) {
      if (tid == 0) __threadfence();
      int quota = (nb >> 6) - (tid == 0 ? 1 : 0);   // leader does not arrive
      while (__hip_atomic_load(&cnt[tid * 16], __ATOMIC_RELAXED,
                               __HIP_MEMORY_SCOPE_AGENT) < quota)
        __builtin_amdgcn_s_sleep(8);
      __hip_atomic_store(&cnt[tid * 16], 0, __ATOMIC_RELAXED,
                         __HIP_MEMORY_SCOPE_AGENT);
    }
    __syncthreads();             // all 64 lines confirmed + reset
    if (tid == 0) {
      __threadfence();
      __hip_atomic_fetch_add(gen, 1, __ATOMIC_RELEASE, __HIP_MEMORY_SCOPE_AGENT);
      __threadfence();
    }
    __syncthreads();
  } else {
    if (tid == 0) {
      int g = __hip_atomic_load(gen, __ATOMIC_RELAXED, __HIP_MEMORY_SCOPE_AGENT);
      __threadfence();
      __hip_atomic_fetch_add(&cnt[(bid & 63) * 16], 1, __ATOMIC_RELEASE,
                             __HIP_MEMORY_SCOPE_AGENT);
      while (__hip_atomic_load(gen, __ATOMIC_ACQUIRE,
                               __HIP_MEMORY_SCOPE_AGENT) == g)
        __builtin_amdgcn_s_sleep(32);
      __threadfence();
    }
    __syncthreads();
  }
}

// ---------------------------------------------------------------------------
// Phase: SPMM layer (2 waves per row, edge-parity split, LDS combine).
// ---------------------------------------------------------------------------
template<int LAYER>
__device__ __forceinline__ void mega_spmm(const MegaArgs& aa, char* smem,
                                          int tid, int bid, int nb) {
  float* part = (float*)smem;   // [2][F]
  const int lane = tid & 63, wh = (tid >> 6) & 1, gl = tid >> 7;
  const int fo = lane << 2;
  for (int tb = bid; tb < (N1 + N2) / 2; tb += nb) {
    const int grp = tb * 2 + gl;
    const bool g2 = grp >= N1;
    const int row = g2 ? grp - N1 : grp;
    const uint2* pe = (g2 ? aa.ell2 : aa.ell1) + (size_t)row * CAP_A;
    const __half* latinh = g2 ? aa.lat2h : aa.lat1h;
    const __half* tailEh = g2 ? aa.dEh : aa.mEh;
    int deg = (g2 ? aa.cur2 : aa.cur1)[(size_t)row * CPAD];
    int dn = deg < CAP_A ? deg : CAP_A;
    float4 s = {0.f, 0.f, 0.f, 0.f};
    auto fetch = [&](int c) -> float4 {
      const __half* b;
      if (LAYER == 1) b = (c < P) ? (aa.pEh + (size_t)c * F) : (tailEh + (size_t)(c - P) * F);
      else            b = latinh + (size_t)c * F;
      return h4_to_f4(b + fo);
    };
    int i = wh;
    for (; i + 15 <= dn; i += 16) {    // 8 edges: i, i+2, ..., i+14
      uint2 m[8]; float4 q[8];
#pragma unroll
      for (int u = 0; u < 8; ++u) m[u] = pe[i + 2 * u];
#pragma unroll
      for (int u = 0; u < 8; ++u) q[u] = fetch((int)m[u].x);
#pragma unroll
      for (int u = 0; u < 8; ++u) {
        float v = __uint_as_float(m[u].y);
        s.x += v * q[u].x; s.y += v * q[u].y; s.z += v * q[u].z; s.w += v * q[u].w;
      }
    }
    for (; i < dn; i += 2) {
      uint2 m = pe[i];
      float v = __uint_as_float(m.y);
      float4 q = fetch((int)m.x);
      s.x += v * q.x; s.y += v * q.y; s.z += v * q.z; s.w += v * q.w;
    }
    if (wh == 1) *(float4*)&part[gl * F + fo] = s;
    __syncthreads();
    if (wh == 0) {
      float4 p = *(const float4*)&part[gl * F + fo];
      s.x += p.x; s.y += p.y; s.z += p.z; s.w += p.w;
      int gi = g2 ? 1 : 0;
      int on = aa.ovf_n[gi];
      if (on > 0) {
        const int4* ol = aa.ovf + gi * OVF_CAP;
        for (int k = 0; k < on; ++k) {
          int4 e = ol[k];
          if (e.x == row) {
            float v = __int_as_float(e.z);
            float4 q = fetch(e.y);
            s.x += v * q.x; s.y += v * q.y; s.z += v * q.z; s.w += v * q.w;
          }
        }
      }
      float4 l;
      l.x = s.x > 0.f ? s.x : 0.5f * s.x;
      l.y = s.y > 0.f ? s.y : 0.5f * s.y;
      l.z = s.z > 0.f ? s.z : 0.5f * s.z;
      l.w = s.w > 0.f ? s.w : 0.5f * s.w;
      if (LAYER == 1) {
        *(float4*)((g2 ? aa.lat2f : aa.lat1f) + (size_t)row * F + fo) = l;
        f4_to_h4((g2 ? aa.lat2h : aa.lat1h) + (size_t)row * F + fo, l);
      } else {
        const float* latf = g2 ? aa.lat2f : aa.lat1f;
        float4 b = *(const float4*)(latf + (size_t)row * F + fo);
        float4 o = {b.x + l.x, b.y + l.y, b.z + l.z, b.w + l.w};
        *(float4*)((g2 ? aa.acc2 : aa.acc1) + (size_t)row * F + fo) = o;
        if (row >= P)
          *(float4*)((g2 ? aa.out_dgcn : aa.out_mgcn) + (size_t)(row - P) * F + fo) = o;
      }
    }
    __syncthreads();
  }
}

// ---------------------------------------------------------------------------
// Phase: all 4 GAT feature GEMMs (FR=8 scalar form, proven).
// ---------------------------------------------------------------------------
__device__ __forceinline__ void mega_feat(const MegaArgs& aa, char* smem,
                                          int tid, int bid, int nb) {
  float* hs = (float*)smem;   // [FR][F]
  const int head = tid >> 6, d = tid & 63;
  for (int b = bid; b < FEAT_BLOCKS; b += nb) {
    int g, rb, n; const float* h; __half* fout;
    if (b < NB0)              { g = 0; rb = b;                n = P; h = aa.acc1;                 fout = aa.f0; }
    else if (b < 2 * NB0)     { g = 1; rb = b - NB0;          n = P; h = aa.acc2;                 fout = aa.f1; }
    else if (b < 2*NB0+NB2)   { g = 2; rb = b - 2 * NB0;      n = M; h = aa.acc1 + (size_t)P * F; fout = aa.f2; }
    else                      { g = 3; rb = b - 2*NB0 - NB2;  n = M; h = aa.acc1 + (size_t)P * F; fout = aa.f3; }
    int elo = (g == 0) ? 0 : (g == 1) ? P * H : (g == 2) ? 2 * P * H : (2 * P + M) * H;
    const float* W = aa.gat_W + (size_t)g * F * F;
    int r0 = rb * FR;
    for (int q = tid; q < FR * 64; q += 256) {
      int r = q >> 6, ln = q & 63;
      int row = r0 + r;
      float4 v = {0.f, 0.f, 0.f, 0.f};
      if (row < n) v = *(const float4*)(h + (size_t)row * F + (ln << 2));
      *(float4*)&hs[r * F + (ln << 2)] = v;
    }
    __syncthreads();
    float acc[FR];
#pragma unroll
    for (int r = 0; r < FR; ++r) acc[r] = 0.f;
    for (int k = 0; k < F; k += 4) {
      float w0 = W[(size_t)k * F + tid],       w1 = W[(size_t)(k + 1) * F + tid],
            w2 = W[(size_t)(k + 2) * F + tid], w3 = W[(size_t)(k + 3) * F + tid];
#pragma unroll
      for (int r = 0; r < FR; ++r) {
        float4 h4 = *(const float4*)&hs[r * F + k];
        acc[r] += h4.x * w0 + h4.y * w1 + h4.z * w2 + h4.w * w3;
      }
    }
    float av = aa.gat_al[g * H * DH + head * DH + d];
    float rv = aa.gat_ar[g * H * DH + head * DH + d];
#pragma unroll
    for (int r = 0; r < FR; ++r) {
      int row = r0 + r;
      if (row < n) {
        fout[(size_t)row * F + tid] = __float2half_rn(acc[r]);
        float cl = acc[r] * av, cr = acc[r] * rv;
        for (int o = 32; o > 0; o >>= 1) {
          cl += __shfl_down(cl, o, 64);
          cr += __shfl_down(cr, o, 64);
        }
        if (d == 0) { aa.el[elo + row * H + head] = cl; aa.er[elo + row * H + head] = cr; }
      }
    }
    __syncthreads();
  }
}

// ---------------------------------------------------------------------------
// Phase: all 4 GAT aggregations (2 waves per dst row, parity split).
// ---------------------------------------------------------------------------
__device__ __forceinline__ void mega_agg(const MegaArgs& aa, char* smem,
                                         int tid, int bid, int nb) {
  float*  mxs  = (float*)smem;             // [2][2][64]
  float4* pacc = (float4*)(smem + 1024);   // [2][64]
  float*  pss  = (float*)(smem + 3072);    // [2][64]
  const int lane = tid & 63, wh = (tid >> 6) & 1, gl = tid >> 7;
  const int head = lane >> 4, fo = lane << 2;
  for (int tb = bid; tb < (2 * P + 2 * M) / 2; tb += nb) {
    const int grp = tb * 2 + gl;
    int g, row; const int* cu; const unsigned* eg; const __half* feat; float* out; int elo;
    if (grp < P)            { g = 0; row = grp;             cu = aa.cu0; eg = aa.eg0; feat = aa.f0; out = aa.e0; elo = 0; }
    else if (grp < 2 * P)   { g = 1; row = grp - P;         cu = aa.cu1; eg = aa.eg1; feat = aa.f1; out = aa.e1; elo = P * H; }
    else if (grp < 2*P + M) { g = 2; row = grp - 2 * P;     cu = aa.cu2; eg = aa.eg2; feat = aa.f2; out = aa.e2; elo = 2 * P * H; }
    else                    { g = 3; row = grp - 2 * P - M; cu = aa.cu3; eg = aa.eg3; feat = aa.f3; out = aa.e3; elo = (2 * P + M) * H; }
    const float* elb = aa.el + elo;
    float erv = aa.er[elo + row * H + head];
    int deg = cu[(size_t)row * CPAD];
    int dn = deg < CAP_G ? deg : CAP_G;
    const unsigned* ps = eg + (size_t)row * CAP_G;
    int on = aa.ovf_n[2 + g];
    const int4* ol = aa.ovf + (2 + g) * OVF_CAP;
    // ---- pass 1: max over this wave's parity edges ----
    float mx = -3.4e38f;
    int i = wh;
    for (; i + 7 <= dn; i += 8) {
      int s0 = (int)ps[i], s1 = (int)ps[i + 2], s2 = (int)ps[i + 4], s3 = (int)ps[i + 6];
      float x = elb[s0 * H + head] + erv, y = elb[s1 * H + head] + erv,
            z = elb[s2 * H + head] + erv, w = elb[s3 * H + head] + erv;
      x = x > 0.f ? x : 0.2f * x; y = y > 0.f ? y : 0.2f * y;
      z = z > 0.f ? z : 0.2f * z; w = w > 0.f ? w : 0.2f * w;
      mx = fmaxf(mx, fmaxf(fmaxf(x, y), fmaxf(z, w)));
    }
    for (; i < dn; i += 2) {
      float x = elb[(int)ps[i] * H + head] + erv;
      x = x > 0.f ? x : 0.2f * x;
      mx = fmaxf(mx, x);
    }
    if (wh == 0 && on > 0) {
      for (int k = 0; k < on; ++k) {
        int4 e = ol[k];
        if (e.x == row) {
          float x = elb[e.y * H + head] + erv;
          x = x > 0.f ? x : 0.2f * x;
          mx = fmaxf(mx, x);
        }
      }
    }
    mxs[(gl * 2 + wh) * 64 + lane] = mx;
    __syncthreads();
    mx = fmaxf(mxs[(gl * 2) * 64 + lane], mxs[(gl * 2 + 1) * 64 + lane]);
    // ---- pass 2: exp-sum + weighted aggregation ----
    float ssum = 0.f;
    float4 acc = {0.f, 0.f, 0.f, 0.f};
    i = wh;
    for (; i + 3 <= dn; i += 4) {
      int s0 = (int)ps[i], s1 = (int)ps[i + 2];
      float x = elb[s0 * H + head] + erv; x = x > 0.f ? x : 0.2f * x;
      float y = elb[s1 * H + head] + erv; y = y > 0.f ? y : 0.2f * y;
      float ex0 = expf(x - mx), ex1 = expf(y - mx);
      float4 q0 = h4_to_f4(feat + (size_t)s0 * F + fo);
      float4 q1 = h4_to_f4(feat + (size_t)s1 * F + fo);
      ssum += ex0 + ex1;
      acc.x += ex0 * q0.x + ex1 * q1.x;
      acc.y += ex0 * q0.y + ex1 * q1.y;
      acc.z += ex0 * q0.z + ex1 * q1.z;
      acc.w += ex0 * q0.w + ex1 * q1.w;
    }
    for (; i < dn; i += 2) {
      int s0 = (int)ps[i];
      float x = elb[s0 * H + head] + erv; x = x > 0.f ? x : 0.2f * x;
      float ex0 = expf(x - mx);
      float4 q0 = h4_to_f4(feat + (size_t)s0 * F + fo);
      ssum += ex0;
      acc.x += ex0 * q0.x; acc.y += ex0 * q0.y; acc.z += ex0 * q0.z; acc.w += ex0 * q0.w;
    }
    if (wh == 1) { pacc[gl * 64 + lane] = acc; pss[gl * 64 + lane] = ssum; }
    __syncthreads();
    if (wh == 0) {
      float4 pa = pacc[gl * 64 + lane];
      acc.x += pa.x; acc.y += pa.y; acc.z += pa.z; acc.w += pa.w;
      ssum += pss[gl * 64 + lane];
      if (on > 0) {
        for (int k = 0; k < on; ++k) {
          int4 e = ol[k];
          if (e.x == row) {
            float x = elb[e.y * H + head] + erv; x = x > 0.f ? x : 0.2f * x;
            float ex0 = expf(x - mx);
            float4 q0 = h4_to_f4(feat + (size_t)e.y * F + fo);
            ssum += ex0;
            acc.x += ex0 * q0.x; acc.y += ex0 * q0.y; acc.z += ex0 * q0.z; acc.w += ex0 * q0.w;
          }
        }
      }
      float inv = 1.f / (ssum + 1e-9f);
      const float* bb = aa.gat_b + g * F + fo;
      float4 v = {acc.x * inv + bb[0], acc.y * inv + bb[1],
                  acc.z * inv + bb[2], acc.w * inv + bb[3]};
      v.x = v.x > 0.f ? v.x : expm1f(v.x);
      v.y = v.y > 0.f ? v.y : expm1f(v.y);
      v.z = v.z > 0.f ? v.z : expm1f(v.z);
      v.w = v.w > 0.f ? v.w : expm1f(v.w);
      *(float4*)(out + (size_t)row * F + fo) = v;
    }
    __syncthreads();
  }
}

// ---------------------------------------------------------------------------
// Phase: semantic attention weights (2 × 128-thread tasks per block).
// ---------------------------------------------------------------------------
__device__ __forceinline__ void mega_sem(const MegaArgs& aa, char* smem,
                                         int tid, int bid, int nb) {
  float* zs = (float*)smem;            // [2][SR][F]
  float* pp = (float*)(smem + 8192);   // [2][2]
  const int sub = tid >> 7, st = tid & 127;
  for (int bt = bid; bt < SEM_BLOCKS / 2; bt += nb) {
    int b = bt * 2 + sub;
    int zid, rb, n; const float* z;
    if (b < SB0)              { zid = 0; rb = b;               n = P; z = aa.e0; }
    else if (b < 2 * SB0)     { zid = 1; rb = b - SB0;         n = P; z = aa.e1; }
    else if (b < 2*SB0+SB2)   { zid = 2; rb = b - 2 * SB0;     n = M; z = aa.e2; }
    else                      { zid = 3; rb = b - 2*SB0 - SB2; n = M; z = aa.e3; }
    float* zsl = zs + sub * (SR * F);
    int r0 = rb * SR;
    for (int q = st; q < SR * 64; q += 128) {
      int r = q >> 6, ln = q & 63;
      int row = r0 + r;
      float4 v = {0.f, 0.f, 0.f, 0.f};
      if (row < n) v = *(const float4*)(z + (size_t)row * F + (ln << 2));
      *(float4*)&zsl[r * F + (ln << 2)] = v;
    }
    __syncthreads();
    float hid[SR];
#pragma unroll
    for (int r = 0; r < SR; ++r) hid[r] = aa.sa_b1[st];
    for (int k = 0; k < F; k += 4) {
      float w0 = aa.sa_W1[(size_t)k * SA_HID + st],       w1 = aa.sa_W1[(size_t)(k + 1) * SA_HID + st],
            w2 = aa.sa_W1[(size_t)(k + 2) * SA_HID + st], w3 = aa.sa_W1[(size_t)(k + 3) * SA_HID + st];
#pragma unroll
      for (int r = 0; r < SR; ++r) {
        float4 z4 = *(const float4*)&zsl[r * F + k];
        hid[r] += z4.x * w0 + z4.y * w1 + z4.z * w2 + z4.w * w3;
      }
    }
    float w2v = aa.sa_W2[st];
    float local = 0.f;
    for (int r = 0; r < SR; ++r) {
      int row = r0 + r;
      if (row < n) local += tanhf(hid[r]) * w2v;
    }
    for (int o = 32; o > 0; o >>= 1) local += __shfl_down(local, o, 64);
    if ((st & 63) == 0) pp[sub * 2 + (st >> 6)] = local;
    __syncthreads();
    if (st == 0) atomicAdd(&aa.wbuf[zid], pp[sub * 2] + pp[sub * 2 + 1]);
    __syncthreads();
  }
}

// ---------------------------------------------------------------------------
// Phase: med beta-combine + relu column-sum sv (parallel across blocks).
// ---------------------------------------------------------------------------
__device__ __forceinline__ void mega_med(const MegaArgs& aa, char* smem,
                                         int tid, int bid, int gtid, int gsz) {
  constexpr int MED4 = M * F / 4;   // 9600
  float m0 = aa.wbuf[2] * (1.f / M), m1 = aa.wbuf[3] * (1.f / M);
  float mxv = fmaxf(m0, m1);
  float b0 = expf(m0 - mxv), b1 = expf(m1 - mxv);
  float sc = 1.f / (b0 + b1);
  b0 *= sc; b1 *= sc;
  float4 rs = {0.f, 0.f, 0.f, 0.f};
  for (int j = gtid; j < MED4; j += gsz) {   // gsz mult of 64 -> j&63 == tid&63
    float4 u0 = ((const float4*)aa.e2)[j], u1 = ((const float4*)aa.e3)[j];
    float4 r = {b0 * u0.x + b1 * u1.x, b0 * u0.y + b1 * u1.y,
                b0 * u0.z + b1 * u1.z, b0 * u0.w + b1 * u1.w};
    ((float4*)aa.out_med)[j] = r;
    rs.x += r.x > 0.f ? r.x : 0.f;
    rs.y += r.y > 0.f ? r.y : 0.f;
    rs.z += r.z > 0.f ? r.z : 0.f;
    rs.w += r.w > 0.f ? r.w : 0.f;
  }
  if (bid * 256 < MED4) {   // only blocks that touched data reduce/atomic
    float4* sv4 = (float4*)smem;   // [4][64]
    sv4[(tid >> 6) * 64 + (tid & 63)] = rs;
    __syncthreads();
    if (tid < 64) {
      float4 x = sv4[tid], y = sv4[64 + tid], z = sv4[128 + tid], w = sv4[192 + tid];
      atomicAdd(&aa.svg[tid * 4 + 0], x.x + y.x + z.x + w.x);
      atomicAdd(&aa.svg[tid * 4 + 1], x.y + y.y + z.y + w.y);
      atomicAdd(&aa.svg[tid * 4 + 2], x.z + y.z + z.z + w.z);
      atomicAdd(&aa.svg[tid * 4 + 3], x.w + y.w + z.w + w.w);
    }
  }
}

// ---------------------------------------------------------------------------
// Phase: patient beta-combine + simi GEMM (c-vector recomputed per block).
// ---------------------------------------------------------------------------
__device__ __forceinline__ void mega_final(const MegaArgs& aa, char* smem,
                                           int tid, int bid, int nb) {
  float* svl = (float*)smem;            // [F]
  float* psh = (float*)(smem + 1024);   // [FIN_R][F]
  for (int q = tid; q < F; q += 256) svl[q] = aa.svg[q];
  float m0 = aa.wbuf[0] * (1.f / P), m1 = aa.wbuf[1] * (1.f / P);
  float mxv = fmaxf(m0, m1);
  float b0 = expf(m0 - mxv), b1 = expf(m1 - mxv);
  float sc = 1.f / (b0 + b1);
  b0 *= sc; b1 *= sc;
  __syncthreads();
  float cv = 0.f;
  if (tid < M) {
    float cacc = 0.f;
    for (int f = 0; f < F; f += 4) {
      cacc += svl[f]     * aa.out_W[(size_t)(F + f)     * M + tid]
            + svl[f + 1] * aa.out_W[(size_t)(F + f + 1) * M + tid]
            + svl[f + 2] * aa.out_W[(size_t)(F + f + 2) * M + tid]
            + svl[f + 3] * aa.out_W[(size_t)(F + f + 3) * M + tid];
    }
    cv = cacc + (float)M * aa.out_b[tid];
  }
  for (int bt = bid; bt < P / FIN_R; bt += nb) {
    int r0 = bt * FIN_R;
    for (int q = tid; q < FIN_R * 64; q += 256) {
      int r = q >> 6, ln = q & 63;
      size_t off = (size_t)(r0 + r) * F + (ln << 2);
      float4 u0 = *(const float4*)(aa.e0 + off), u1 = *(const float4*)(aa.e1 + off);
      float4 v = {b0 * u0.x + b1 * u1.x, b0 * u0.y + b1 * u1.y,
                  b0 * u0.z + b1 * u1.z, b0 * u0.w + b1 * u1.w};
      *(float4*)(aa.out_pat + off) = v;
      v.x = v.x > 0.f ? v.x : 0.f; v.y = v.y > 0.f ? v.y : 0.f;
      v.z = v.z > 0.f ? v.z : 0.f; v.w = v.w > 0.f ? v.w : 0.f;
      *(float4*)&psh[r * F + (ln << 2)] = v;
    }
    __syncthreads();
    if (tid < M) {
      float acc[FIN_R];
#pragma unroll
      for (int r = 0; r < FIN_R; ++r) acc[r] = 0.f;
      for (int f = 0; f < F; f += 4) {
        float w0 = aa.out_W[(size_t)f * M + tid],       w1 = aa.out_W[(size_t)(f + 1) * M + tid],
              w2 = aa.out_W[(size_t)(f + 2) * M + tid], w3 = aa.out_W[(size_t)(f + 3) * M + tid];
#pragma unroll
        for (int r = 0; r < FIN_R; ++r) {
          float4 p4 = *(const float4*)&psh[r * F + f];
          acc[r] += p4.x * w0 + p4.y * w1 + p4.z * w2 + p4.w * w3;
        }
      }
#pragma unroll
      for (int r = 0; r < FIN_R; ++r)
        aa.out_simi[(size_t)(r0 + r) * M + tid] = (float)M * acc[r] + cv;
    }
    __syncthreads();
  }
}

// ===========================================================================
// Persistent mega-kernel: 8 phases, 7 custom barriers (counters zeroed by
// the host memset that precedes the launch).
// ===========================================================================
__global__ __launch_bounds__(256) void k_mega(MegaArgs aa) {
  const int tid = threadIdx.x, bid = blockIdx.x, nb = gridDim.x;
  const int gtid = bid * 256 + tid, gsz = nb * 256;
  __shared__ __align__(16) char smem[8448];

  // ---- P1: ELL build + fused fp32->fp16 embed cast ----
  for (int i = gtid; i < HOE; i += gsz) {
    if (i < HO1) {
      int r = aa.a1r[i]; unsigned q0 = (unsigned)aa.a1c[i], q1 = __float_as_uint(aa.a1v[i]);
      int slot = atomicAdd(&aa.cur1[(size_t)r * CPAD], 1);
      if (slot < CAP_A) aa.ell1[(size_t)r * CAP_A + slot] = make_uint2(q0, q1);
      else { int o = atomicAdd(&aa.ovf_n[0], 1); if (o < OVF_CAP) aa.ovf[0 * OVF_CAP + o] = make_int4(r, (int)q0, (int)q1, 0); }
    } else if (i < HO2) {
      int j = i - HO1;
      int r = aa.a2r[j]; unsigned q0 = (unsigned)aa.a2c[j], q1 = __float_as_uint(aa.a2v[j]);
      int slot = atomicAdd(&aa.cur2[(size_t)r * CPAD], 1);
      if (slot < CAP_A) aa.ell2[(size_t)r * CAP_A + slot] = make_uint2(q0, q1);
      else { int o = atomicAdd(&aa.ovf_n[1], 1); if (o < OVF_CAP) aa.ovf[1 * OVF_CAP + o] = make_int4(r, (int)q0, (int)q1, 0); }
    } else if (i < HO3) {
      int j = i - HO2;
      int r = aa.g0d[j]; unsigned q0 = (unsigned)aa.g0s[j];
      int slot = atomicAdd(&aa.cu0[(size_t)r * CPAD], 1);
      if (slot < CAP_G) aa.eg0[(size_t)r * CAP_G + slot] = q0;
      else { int o = atomicAdd(&aa.ovf_n[2], 1); if (o < OVF_CAP) aa.ovf[2 * OVF_CAP + o] = make_int4(r, (int)q0, 0, 0); }
    } else if (i < HO4) {
      int j = i - HO3;
      int r = aa.g1d[j]; unsigned q0 = (unsigned)aa.g1s[j];
      int slot = atomicAdd(&aa.cu1[(size_t)r * CPAD], 1);
      if (slot < CAP_G) aa.eg1[(size_t)r * CAP_G + slot] = q0;
      else { int o = atomicAdd(&aa.ovf_n[3], 1); if (o < OVF_CAP) aa.ovf[3 * OVF_CAP + o] = make_int4(r, (int)q0, 0, 0); }
    } else if (i < HO5) {
      int j = i - HO4;
      int r = aa.g2d[j]; unsigned q0 = (unsigned)aa.g2s[j];
      int slot = atomicAdd(&aa.cu2[(size_t)r * CPAD], 1);
      if (slot < CAP_G) aa.eg2[(size_t)r * CAP_G + slot] = q0;
      else { int o = atomicAdd(&aa.ovf_n[4], 1); if (o < OVF_CAP) aa.ovf[4 * OVF_CAP + o] = make_int4(r, (int)q0, 0, 0); }
    } else {
      int j = i - HO5;
      int r = aa.g3d[j]; unsigned q0 = (unsigned)aa.g3s[j];
      int slot = atomicAdd(&aa.cu3[(size_t)r * CPAD], 1);
      if (slot < CAP_G) aa.eg3[(size_t)r * CAP_G + slot] = q0;
      else { int o = atomicAdd(&aa.ovf_n[5], 1); if (o < OVF_CAP) aa.ovf[5 * OVF_CAP + o] = make_int4(r, (int)q0, 0, 0); }
    }
  }
  for (int c = gtid; c < CAST_CH; c += gsz) {
    int j = c * 8;
    const float* src; __half* dst;
    if (j < P * F)              { src = aa.pE + j;                 dst = aa.pEh + j; }
    else if (j < P * F + M * F) { src = aa.mE + (j - P * F);       dst = aa.mEh + (j - P * F); }
    else                        { src = aa.dE + (j - P*F - M*F);   dst = aa.dEh + (j - P*F - M*F); }
    float4 x = *(const float4*)src, y = *(const float4*)(src + 4);
    f4_to_h4(dst, x);
    f4_to_h4(dst + 4, y);
  }
  gbarrier(aa.bcnt, aa.bgen, nb, bid, tid);

  mega_spmm<1>(aa, smem, tid, bid, nb);
  gbarrier(aa.bcnt, aa.bgen, nb, bid, tid);
  mega_spmm<2>(aa, smem, tid, bid, nb);
  gbarrier(aa.bcnt, aa.bgen, nb, bid, tid);
  mega_feat(aa, smem, tid, bid, nb);
  gbarrier(aa.bcnt, aa.bgen, nb, bid, tid);
  mega_agg(aa, smem, tid, bid, nb);
  gbarrier(aa.bcnt, aa.bgen, nb, bid, tid);
  mega_sem(aa, smem, tid, bid, nb);
  gbarrier(aa.bcnt, aa.bgen, nb, bid, tid);
  mega_med(aa, smem, tid, bid, gtid, gsz);
  gbarrier(aa.bcnt, aa.bgen, nb, bid, tid);
  mega_final(aa, smem, tid, bid, nb);
}

// ===========================================================================
// ============ Legacy fallback path (proven 10-dispatch pipeline) ===========
// ===========================================================================
__global__ __launch_bounds__(256) void k_build(
    const int* __restrict__ a1r, const int* __restrict__ a1c, const float* __restrict__ a1v,
    const int* __restrict__ a2r, const int* __restrict__ a2c, const float* __restrict__ a2v,
    const int* __restrict__ d0, const int* __restrict__ s0,
    const int* __restrict__ d1, const int* __restrict__ s1,
    const int* __restrict__ d2, const int* __restrict__ s2,
    const int* __restrict__ d3, const int* __restrict__ s3,
    int* cur1, uint2* ell1, int* cur2, uint2* ell2,
    int* cu0, unsigned* eg0, int* cu1, unsigned* eg1,
    int* cu2, unsigned* eg2, int* cu3, unsigned* eg3,
    int* __restrict__ ovf_n, int4* __restrict__ ovf,
    const float* __restrict__ pEf, const float* __restrict__ mEf,
    const float* __restrict__ dEf,
    __half* __restrict__ pEh, __half* __restrict__ mEh, __half* __restrict__ dEh) {
  int tid = blockIdx.x * 256 + threadIdx.x;
  int T = gridDim.x * 256;
  int seg[4], row[4]; unsigned p0[4], p1[4];
#pragma unroll
  for (int u = 0; u < 4; ++u) {
    int i = tid + u * T;
    seg[u] = -1;
    if (i < HOE) {
      if (i < HO1)      { seg[u] = 0; row[u] = a1r[i]; p0[u] = (unsigned)a1c[i]; p1[u] = __float_as_uint(a1v[i]); }
      else if (i < HO2) { int j = i - HO1; seg[u] = 1; row[u] = a2r[j]; p0[u] = (unsigned)a2c[j]; p1[u] = __float_as_uint(a2v[j]); }
      else if (i < HO3) { int j = i - HO2; seg[u] = 2; row[u] = d0[j]; p0[u] = (unsigned)s0[j]; }
      else if (i < HO4) { int j = i - HO3; seg[u] = 3; row[u] = d1[j]; p0[u] = (unsigned)s1[j]; }
      else if (i < HO5) { int j = i - HO4; seg[u] = 4; row[u] = d2[j]; p0[u] = (unsigned)s2[j]; }
      else              { int j = i - HO5; seg[u] = 5; row[u] = d3[j]; p0[u] = (unsigned)s3[j]; }
    }
  }
#pragma unroll
  for (int u = 0; u < 4; ++u) {
    int r = row[u];
    switch (seg[u]) {
      case 0: { int slot = atomicAdd(&cur1[(size_t)r * CPAD], 1);
        if (slot < CAP_A) ell1[(size_t)r * CAP_A + slot] = make_uint2(p0[u], p1[u]);
        else { int o = atomicAdd(&ovf_n[0], 1); if (o < OVF_CAP) ovf[0 * OVF_CAP + o] = make_int4(r, (int)p0[u], (int)p1[u], 0); } } break;
      case 1: { int slot = atomicAdd(&cur2[(size_t)r * CPAD], 1);
        if (slot < CAP_A) ell2[(size_t)r * CAP_A + slot] = make_uint2(p0[u], p1[u]);
        else { int o = atomicAdd(&ovf_n[1], 1); if (o < OVF_CAP) ovf[1 * OVF_CAP + o] = make_int4(r, (int)p0[u], (int)p1[u], 0); } } break;
      case 2: { int slot = atomicAdd(&cu0[(size_t)r * CPAD], 1);
        if (slot < CAP_G) eg0[(size_t)r * CAP_G + slot] = p0[u];
        else { int o = atomicAdd(&ovf_n[2], 1); if (o < OVF_CAP) ovf[2 * OVF_CAP + o] = make_int4(r, (int)p0[u], 0, 0); } } break;
      case 3: { int slot = atomicAdd(&cu1[(size_t)r * CPAD], 1);
        if (slot < CAP_G) eg1[(size_t)r * CAP_G + slot] = p0[u];
        else { int o = atomicAdd(&ovf_n[3], 1); if (o < OVF_CAP) ovf[3 * OVF_CAP + o] = make_int4(r, (int)p0[u], 0, 0); } } break;
      case 4: { int slot = atomicAdd(&cu2[(size_t)r * CPAD], 1);
        if (slot < CAP_G) eg2[(size_t)r * CAP_G + slot] = p0[u];
        else { int o = atomicAdd(&ovf_n[4], 1); if (o < OVF_CAP) ovf[4 * OVF_CAP + o] = make_int4(r, (int)p0[u], 0, 0); } } break;
      case 5: { int slot = atomicAdd(&cu3[(size_t)r * CPAD], 1);
        if (slot < CAP_G) eg3[(size_t)r * CAP_G + slot] = p0[u];
        else { int o = atomicAdd(&ovf_n[5], 1); if (o < OVF_CAP) ovf[5 * OVF_CAP + o] = make_int4(r, (int)p0[u], 0, 0); } } break;
      default: break;
    }
  }
  for (int c = tid; c < CAST_CH; c += T) {
    int j = c * 8;
    const float* src; __half* dst;
    if (j < P * F)              { src = pEf + j;               dst = pEh + j; }
    else if (j < P * F + M * F) { src = mEf + (j - P * F);     dst = mEh + (j - P * F); }
    else                        { src = dEf + (j - P*F - M*F); dst = dEh + (j - P*F - M*F); }
    float4 x = *(const float4*)src, y = *(const float4*)(src + 4);
    f4_to_h4(dst, x);
    f4_to_h4(dst + 4, y);
  }
}

template<int LAYER>
__global__ __launch_bounds__(256) void k_spmm(
    const int* __restrict__ cur1, const uint2* __restrict__ ell1,
    const int* __restrict__ cur2, const uint2* __restrict__ ell2,
    const int* __restrict__ ovf_n, const int4* __restrict__ ovf,
    const __half* __restrict__ pEh, const __half* __restrict__ mEh,
    const __half* __restrict__ dEh,
    float* __restrict__ lat1f, float* __restrict__ lat2f,
    __half* __restrict__ lat1h, __half* __restrict__ lat2h,
    float* __restrict__ acc1, float* __restrict__ acc2,
    float* __restrict__ out_mgcn, float* __restrict__ out_dgcn) {
  int grp = (blockIdx.x * 256 + threadIdx.x) >> 7;
  int lane = threadIdx.x & 63;
  int wh   = (threadIdx.x >> 6) & 1;
  int gl   = threadIdx.x >> 7;
  bool g2 = grp >= N1;
  int row = g2 ? grp - N1 : grp;
  const uint2* pe = (g2 ? ell2 : ell1) + (size_t)row * CAP_A;
  const __half* latinh = g2 ? lat2h : lat1h;
  const __half* tailEh = g2 ? dEh : mEh;
  int deg = (g2 ? cur2 : cur1)[(size_t)row * CPAD];
  int dn = deg < CAP_A ? deg : CAP_A;
  int fo = lane << 2;
  float4 s = {0.f, 0.f, 0.f, 0.f};
  auto fetch = [&](int c) -> float4 {
    const __half* b;
    if (LAYER == 1) b = (c < P) ? (pEh + (size_t)c * F) : (tailEh + (size_t)(c - P) * F);
    else            b = latinh + (size_t)c * F;
    return h4_to_f4(b + fo);
  };
  int i = wh;
  for (; i + 15 <= dn; i += 16) {
    uint2 m[8]; float4 a[8];
#pragma unroll
    for (int u = 0; u < 8; ++u) m[u] = pe[i + 2 * u];
#pragma unroll
    for (int u = 0; u < 8; ++u) a[u] = fetch((int)m[u].x);
#pragma unroll
    for (int u = 0; u < 8; ++u) {
      float v = __uint_as_float(m[u].y);
      s.x += v * a[u].x; s.y += v * a[u].y; s.z += v * a[u].z; s.w += v * a[u].w;
    }
  }
  for (; i < dn; i += 2) {
    uint2 m = pe[i];
    float v = __uint_as_float(m.y);
    float4 a = fetch((int)m.x);
    s.x += v * a.x; s.y += v * a.y; s.z += v * a.z; s.w += v * a.w;
  }
  __shared__ float part[2][F];
  if (wh == 1) *(float4*)&part[gl][fo] = s;
  __syncthreads();
  if (wh == 1) return;
  {
    float4 p = *(const float4*)&part[gl][fo];
    s.x += p.x; s.y += p.y; s.z += p.z; s.w += p.w;
  }
  {
    int gi = g2 ? 1 : 0;
    int on = ovf_n[gi];
    if (on > 0) {
      const int4* ol = ovf + gi * OVF_CAP;
      for (int k = 0; k < on; ++k) {
        int4 e = ol[k];
        if (e.x == row) {
          float v = __int_as_float(e.z);
          float4 a = fetch(e.y);
          s.x += v * a.x; s.y += v * a.y; s.z += v * a.z; s.w += v * a.w;
        }
      }
    }
  }
  float4 l;
  l.x = s.x > 0.f ? s.x : 0.5f * s.x;
  l.y = s.y > 0.f ? s.y : 0.5f * s.y;
  l.z = s.z > 0.f ? s.z : 0.5f * s.z;
  l.w = s.w > 0.f ? s.w : 0.5f * s.w;
  if (LAYER == 1) {
    *(float4*)((g2 ? lat2f : lat1f) + (size_t)row * F + fo) = l;
    f4_to_h4((g2 ? lat2h : lat1h) + (size_t)row * F + fo, l);
  } else {
    const float* latf = g2 ? lat2f : lat1f;
    float4 b = *(const float4*)(latf + (size_t)row * F + fo);
    float4 a = {b.x + l.x, b.y + l.y, b.z + l.z, b.w + l.w};
    *(float4*)((g2 ? acc2 : acc1) + (size_t)row * F + fo) = a;
    if (row >= P)
      *(float4*)((g2 ? out_dgcn : out_mgcn) + (size_t)(row - P) * F + fo) = a;
  }
}

__global__ __launch_bounds__(256) void k_gat_feat_all(
    const float* __restrict__ acc1, const float* __restrict__ acc2,
    const float* __restrict__ gat_W, const float* __restrict__ gat_al,
    const float* __restrict__ gat_ar,
    __half* __restrict__ f0, __half* __restrict__ f1,
    __half* __restrict__ f2, __half* __restrict__ f3,
    float* __restrict__ el, float* __restrict__ er) {
  int b = blockIdx.x;
  int g, rb, n; const float* h; __half* fout;
  if (b < NB0)            { g = 0; rb = b;              n = P; h = acc1; fout = f0; }
  else if (b < 2 * NB0)   { g = 1; rb = b - NB0;        n = P; h = acc2; fout = f1; }
  else if (b < 2*NB0+NB2) { g = 2; rb = b - 2 * NB0;    n = M; h = acc1 + (size_t)P * F; fout = f2; }
  else                    { g = 3; rb = b - 2*NB0 - NB2; n = M; h = acc1 + (size_t)P * F; fout = f3; }
  int elo = (g == 0) ? 0 : (g == 1) ? P * H : (g == 2) ? 2 * P * H : (2 * P + M) * H;
  const float* W = gat_W + (size_t)g * F * F;
  __shared__ float hs[FR][F];
  int t = threadIdx.x;
  int r0 = rb * FR;
  for (int q = t; q < FR * 64; q += 256) {
    int r = q >> 6, ln = q & 63;
    int row = r0 + r;
    float4 v = {0.f, 0.f, 0.f, 0.f};
    if (row < n) v = *(const float4*)(h + (size_t)row * F + (ln << 2));
    *(float4*)&hs[r][ln << 2] = v;
  }
  __syncthreads();
  float acc[FR];
#pragma unroll
  for (int r = 0; r < FR; ++r) acc[r] = 0.f;
  for (int k = 0; k < F; k += 4) {
    float w0 = W[(size_t)k * F + t],       w1 = W[(size_t)(k + 1) * F + t],
          w2 = W[(size_t)(k + 2) * F + t], w3 = W[(size_t)(k + 3) * F + t];
#pragma unroll
    for (int r = 0; r < FR; ++r) {
      float4 h4 = *(const float4*)&hs[r][k];
      acc[r] += h4.x * w0 + h4.y * w1 + h4.z * w2 + h4.w * w3;
    }
  }
  int head = t >> 6, d = t & 63;
  float av = gat_al[g * H * DH + head * DH + d];
  float rv = gat_ar[g * H * DH + head * DH + d];
#pragma unroll
  for (int r = 0; r < FR; ++r) {
    int row = r0 + r;
    if (row < n) {
      fout[(size_t)row * F + t] = __float2half_rn(acc[r]);
      float cl = acc[r] * av, cr = acc[r] * rv;
      for (int o = 32; o > 0; o >>= 1) {
        cl += __shfl_down(cl, o, 64);
        cr += __shfl_down(cr, o, 64);
      }
      if (d == 0) { el[elo + row * H + head] = cl; er[elo + row * H + head] = cr; }
    }
  }
}

__global__ __launch_bounds__(256) void k_gat_agg_all(
    const int* __restrict__ cu0, const unsigned* __restrict__ eg0,
    const int* __restrict__ cu1, const unsigned* __restrict__ eg1,
    const int* __restrict__ cu2, const unsigned* __restrict__ eg2,
    const int* __restrict__ cu3, const unsigned* __restrict__ eg3,
    const int* __restrict__ ovf_n, const int4* __restrict__ ovf,
    const float* __restrict__ el, const float* __restrict__ er,
    const __half* __restrict__ f0, const __half* __restrict__ f1,
    const __half* __restrict__ f2, const __half* __restrict__ f3,
    const float* __restrict__ gat_b,
    float* __restrict__ e0, float* __restrict__ e1,
    float* __restrict__ e2, float* __restrict__ e3) {
  int grp = (blockIdx.x * 256 + threadIdx.x) >> 7;
  int lane = threadIdx.x & 63;
  int wh   = (threadIdx.x >> 6) & 1;
  int gl   = threadIdx.x >> 7;
  int g, row; const int* cu; const unsigned* eg; const __half* feat; float* out; int elo;
  if (grp < P)            { g = 0; row = grp;             cu = cu0; eg = eg0; feat = f0; out = e0; elo = 0; }
  else if (grp < 2 * P)   { g = 1; row = grp - P;         cu = cu1; eg = eg1; feat = f1; out = e1; elo = P * H; }
  else if (grp < 2*P + M) { g = 2; row = grp - 2 * P;     cu = cu2; eg = eg2; feat = f2; out = e2; elo = 2 * P * H; }
  else                    { g = 3; row = grp - 2 * P - M; cu = cu3; eg = eg3; feat = f3; out = e3; elo = (2 * P + M) * H; }
  int head = lane >> 4;
  int fo = lane << 2;
  const float* elb = el + elo;
  float erv = er[elo + row * H + head];
  int deg = cu[(size_t)row * CPAD];
  int dn = deg < CAP_G ? deg : CAP_G;
  const unsigned* ps = eg + (size_t)row * CAP_G;
  int on = ovf_n[2 + g];
  const int4* ol = ovf + (2 + g) * OVF_CAP;
  float mx = -3.4e38f;
  int i = wh;
  for (; i + 7 <= dn; i += 8) {
    int s0 = (int)ps[i], s1 = (int)ps[i + 2], s2 = (int)ps[i + 4], s3 = (int)ps[i + 6];
    float a = elb[s0 * H + head] + erv, b = elb[s1 * H + head] + erv,
          c = elb[s2 * H + head] + erv, d = elb[s3 * H + head] + erv;
    a = a > 0.f ? a : 0.2f * a; b = b > 0.f ? b : 0.2f * b;
    c = c > 0.f ? c : 0.2f * c; d = d > 0.f ? d : 0.2f * d;
    mx = fmaxf(mx, fmaxf(fmaxf(a, b), fmaxf(c, d)));
  }
  for (; i < dn; i += 2) {
    float a = elb[(int)ps[i] * H + head] + erv;
    a = a > 0.f ? a : 0.2f * a;
    mx = fmaxf(mx, a);
  }
  if (wh == 0 && on > 0) {
    for (int k = 0; k < on; ++k) {
      int4 e = ol[k];
      if (e.x == row) {
        float a = elb[e.y * H + head] + erv;
        a = a > 0.f ? a : 0.2f * a;
        mx = fmaxf(mx, a);
      }
    }
  }
  __shared__ float mxs[2][2][64];
  mxs[gl][wh][lane] = mx;
  __syncthreads();
  mx = fmaxf(mxs[gl][0][lane], mxs[gl][1][lane]);
  float ssum = 0.f;
  float4 acc = {0.f, 0.f, 0.f, 0.f};
  i = wh;
  for (; i + 3 <= dn; i += 4) {
    int s0 = (int)ps[i], s1 = (int)ps[i + 2];
    float a = elb[s0 * H + head] + erv; a = a > 0.f ? a : 0.2f * a;
    float b = elb[s1 * H + head] + erv; b = b > 0.f ? b : 0.2f * b;
    float x0 = expf(a - mx), x1 = expf(b - mx);
    float4 q0 = h4_to_f4(feat + (size_t)s0 * F + fo);
    float4 q1 = h4_to_f4(feat + (size_t)s1 * F + fo);
    ssum += x0 + x1;
    acc.x += x0 * q0.x + x1 * q1.x;
    acc.y += x0 * q0.y + x1 * q1.y;
    acc.z += x0 * q0.z + x1 * q1.z;
    acc.w += x0 * q0.w + x1 * q1.w;
  }
  for (; i < dn; i += 2) {
    int s0 = (int)ps[i];
    float a = elb[s0 * H + head] + erv; a = a > 0.f ? a : 0.2f * a;
    float x0 = expf(a - mx);
    float4 q0 = h4_to_f4(feat + (size_t)s0 * F + fo);
    ssum += x0;
    acc.x += x0 * q0.x; acc.y += x0 * q0.y; acc.z += x0 * q0.z; acc.w += x0 * q0.w;
  }
  __shared__ float4 pacc[2][64];
  __shared__ float  pss[2][64];
  if (wh == 1) { pacc[gl][lane] = acc; pss[gl][lane] = ssum; }
  __syncthreads();
  if (wh == 1) return;
  {
    float4 pa = pacc[gl][lane];
    acc.x += pa.x; acc.y += pa.y; acc.z += pa.z; acc.w += pa.w;
    ssum += pss[gl][lane];
  }
  if (on > 0) {
    for (int k = 0; k < on; ++k) {
      int4 e = ol[k];
      if (e.x == row) {
        float a = elb[e.y * H + head] + erv; a = a > 0.f ? a : 0.2f * a;
        float x0 = expf(a - mx);
        float4 q0 = h4_to_f4(feat + (size_t)e.y * F + fo);
        ssum += x0;
        acc.x += x0 * q0.x; acc.y += x0 * q0.y; acc.z += x0 * q0.z; acc.w += x0 * q0.w;
      }
    }
  }
  float inv = 1.f / (ssum + 1e-9f);
  const float* bb = gat_b + g * F + fo;
  float4 v = {acc.x * inv + bb[0], acc.y * inv + bb[1],
              acc.z * inv + bb[2], acc.w * inv + bb[3]};
  v.x = v.x > 0.f ? v.x : expm1f(v.x);
  v.y = v.y > 0.f ? v.y : expm1f(v.y);
  v.z = v.z > 0.f ? v.z : expm1f(v.z);
  v.w = v.w > 0.f ? v.w : expm1f(v.w);
  *(float4*)(out + (size_t)row * F + fo) = v;
}

__global__ __launch_bounds__(128) void k_sem_w_all(
    const float* __restrict__ e0, const float* __restrict__ e1,
    const float* __restrict__ e2, const float* __restrict__ e3,
    const float* __restrict__ W1, const float* __restrict__ b1,
    const float* __restrict__ W2, float* __restrict__ w) {
  int b = blockIdx.x;
  int zid, rb, n; const float* z;
  if (b < SB0)            { zid = 0; rb = b;             n = P; z = e0; }
  else if (b < 2 * SB0)   { zid = 1; rb = b - SB0;       n = P; z = e1; }
  else if (b < 2*SB0+SB2) { zid = 2; rb = b - 2 * SB0;   n = M; z = e2; }
  else                    { zid = 3; rb = b - 2*SB0-SB2; n = M; z = e3; }
  __shared__ float zs[SR][F];
  int t = threadIdx.x;
  int r0 = rb * SR;
  for (int q = t; q < SR * 64; q += 128) {
    int r = q >> 6, ln = q & 63;
    int row = r0 + r;
    float4 v = {0.f, 0.f, 0.f, 0.f};
    if (row < n) v = *(const float4*)(z + (size_t)row * F + (ln << 2));
    *(float4*)&zs[r][ln << 2] = v;
  }
  __syncthreads();
  float hid[SR];
#pragma unroll
  for (int r = 0; r < SR; ++r) hid[r] = b1[t];
  for (int k = 0; k < F; k += 4) {
    float w0 = W1[(size_t)k * SA_HID + t],       w1 = W1[(size_t)(k + 1) * SA_HID + t],
          w2 = W1[(size_t)(k + 2) * SA_HID + t], w3 = W1[(size_t)(k + 3) * SA_HID + t];
#pragma unroll
    for (int r = 0; r < SR; ++r) {
      float4 z4 = *(const float4*)&zs[r][k];
      hid[r] += z4.x * w0 + z4.y * w1 + z4.z * w2 + z4.w * w3;
    }
  }
  float w2v = W2[t];
  float local = 0.f;
  for (int r = 0; r < SR; ++r) {
    int row = r0 + r;
    if (row < n) local += tanhf(hid[r]) * w2v;
  }
  for (int o = 32; o > 0; o >>= 1) local += __shfl_down(local, o, 64);
  __shared__ float pp[2];
  if ((t & 63) == 0) pp[t >> 6] = local;
  __syncthreads();
  if (t == 0) atomicAdd(&w[zid], pp[0] + pp[1]);
}

__global__ __launch_bounds__(256) void k_med_cvec(
    const float* __restrict__ e2, const float* __restrict__ e3,
    const float* __restrict__ w, const float* __restrict__ outW,
    const float* __restrict__ outb,
    float* __restrict__ out_med, float* __restrict__ cbuf) {
  int t = threadIdx.x;
  float m0 = w[2] * (1.f / M), m1 = w[3] * (1.f / M);
  float mxv = fmaxf(m0, m1);
  float a0 = expf(m0 - mxv), a1 = expf(m1 - mxv);
  float sc = 1.f / (a0 + a1);
  a0 *= sc; a1 *= sc;
  float4 rs = {0.f, 0.f, 0.f, 0.f};
  for (int j = t; j < M * F / 4; j += 256) {
    float4 u0 = ((const float4*)e2)[j], u1 = ((const float4*)e3)[j];
    float4 r = {a0 * u0.x + a1 * u1.x, a0 * u0.y + a1 * u1.y,
                a0 * u0.z + a1 * u1.z, a0 * u0.w + a1 * u1.w};
    ((float4*)out_med)[j] = r;
    rs.x += r.x > 0.f ? r.x : 0.f;
    rs.y += r.y > 0.f ? r.y : 0.f;
    rs.z += r.z > 0.f ? r.z : 0.f;
    rs.w += r.w > 0.f ? r.w : 0.f;
  }
  __shared__ float4 sv4[4][64];
  sv4[t >> 6][t & 63] = rs;
  __syncthreads();
  __shared__ float sv[F];
  if (t < 64) {
    float4 a = sv4[0][t], b = sv4[1][t], c = sv4[2][t], d = sv4[3][t];
    sv[t * 4 + 0] = a.x + b.x + c.x + d.x;
    sv[t * 4 + 1] = a.y + b.y + c.y + d.y;
    sv[t * 4 + 2] = a.z + b.z + c.z + d.z;
    sv[t * 4 + 3] = a.w + b.w + c.w + d.w;
  }
  __syncthreads();
  if (t < M) {
    float cc = (float)M * outb[t];
    for (int f = 0; f < F; f += 4) {
      cc += sv[f]     * outW[(size_t)(F + f) * M + t]
          + sv[f + 1] * outW[(size_t)(F + f + 1) * M + t]
          + sv[f + 2] * outW[(size_t)(F + f + 2) * M + t]
          + sv[f + 3] * outW[(size_t)(F + f + 3) * M + t];
    }
    cbuf[t] = cc;
  }
}

__global__ __launch_bounds__(256) void k_final(
    const float* __restrict__ e0, const float* __restrict__ e1,
    const float* __restrict__ w, const float* __restrict__ outW,
    const float* __restrict__ c,
    float* __restrict__ out_pat, float* __restrict__ simi) {
  float m0 = w[0] * (1.f / P), m1 = w[1] * (1.f / P);
  float mxv = fmaxf(m0, m1);
  float a0 = expf(m0 - mxv), a1 = expf(m1 - mxv);
  float sc = 1.f / (a0 + a1);
  a0 *= sc; a1 *= sc;
  __shared__ float psh[FIN_R][F];
  int t = threadIdx.x;
  int r0 = blockIdx.x * FIN_R;
  for (int q = t; q < FIN_R * 64; q += 256) {
    int r = q >> 6, ln = q & 63;
    size_t off = (size_t)(r0 + r) * F + (ln << 2);
    float4 u0 = *(const float4*)(e0 + off), u1 = *(const float4*)(e1 + off);
    float4 v = {a0 * u0.x + a1 * u1.x, a0 * u0.y + a1 * u1.y,
                a0 * u0.z + a1 * u1.z, a0 * u0.w + a1 * u1.w};
    *(float4*)(out_pat + off) = v;
    v.x = v.x > 0.f ? v.x : 0.f; v.y = v.y > 0.f ? v.y : 0.f;
    v.z = v.z > 0.f ? v.z : 0.f; v.w = v.w > 0.f ? v.w : 0.f;
    *(float4*)&psh[r][ln << 2] = v;
  }
  __syncthreads();
  if (t < M) {
    float acc[FIN_R];
#pragma unroll
    for (int r = 0; r < FIN_R; ++r) acc[r] = 0.f;
    for (int f = 0; f < F; f += 4) {
      float w0 = outW[(size_t)f * M + t],       w1 = outW[(size_t)(f + 1) * M + t],
            w2 = outW[(size_t)(f + 2) * M + t], w3 = outW[(size_t)(f + 3) * M + t];
#pragma unroll
      for (int r = 0; r < FIN_R; ++r) {
        float4 p4 = *(const float4*)&psh[r][f];
        acc[r] += p4.x * w0 + p4.y * w1 + p4.z * w2 + p4.w * w3;
      }
    }
    float cv = c[t];
    for (int r = 0; r < FIN_R; ++r)
      simi[(size_t)(r0 + r) * M + t] = (float)M * acc[r] + cv;
  }
}

// ---------------------------------------------------------------------------
extern "C" void kernel_launch(void* const* d_in, const int* in_sizes, int n_in,
                              void* d_out, int out_size, void* d_ws, size_t ws_size,
                              hipStream_t stream) {
  const int*   adj1_rows = (const int*)d_in[0];
  const int*   adj1_cols = (const int*)d_in[1];
  const float* adj1_vals = (const float*)d_in[2];
  const int*   adj2_rows = (const int*)d_in[3];
  const int*   adj2_cols = (const int*)d_in[4];
  const float* adj2_vals = (const float*)d_in[5];
  const int*   g0_src = (const int*)d_in[6];
  const int*   g0_dst = (const int*)d_in[7];
  const int*   g1_src = (const int*)d_in[8];
  const int*   g1_dst = (const int*)d_in[9];
  const int*   g2_src = (const int*)d_in[10];
  const int*   g2_dst = (const int*)d_in[11];
  const int*   g3_src = (const int*)d_in[12];
  const int*   g3_dst = (const int*)d_in[13];
  // d_in[14] = keepRate (unused, == 1)
  const float* pE     = (const float*)d_in[15];
  const float* mE     = (const float*)d_in[16];
  const float* dE     = (const float*)d_in[17];
  const float* gat_W  = (const float*)d_in[18];
  const float* gat_al = (const float*)d_in[19];
  const float* gat_ar = (const float*)d_in[20];
  const float* gat_b  = (const float*)d_in[21];
  const float* sa_W1  = (const float*)d_in[22];
  const float* sa_b1  = (const float*)d_in[23];
  const float* sa_W2  = (const float*)d_in[24];
  const float* out_W  = (const float*)d_in[25];
  const float* out_b  = (const float*)d_in[26];

  // ---- workspace layout: [zeroed region | ELL | fp16 | fp32] ----
  int* ip = (int*)d_ws;
  int* bar_cnt = ip; ip += 64 * 16;           // 64 barrier arrival lines
  int* bar_gen = ip; ip += 16;                // generation flag (own line)
  int* cur1 = ip; ip += (size_t)N1 * CPAD;
  int* cur2 = ip; ip += (size_t)N2 * CPAD;
  int* cu0  = ip; ip += (size_t)P * CPAD;
  int* cu1  = ip; ip += (size_t)P * CPAD;
  int* cu2  = ip; ip += (size_t)M * CPAD;
  int* cu3  = ip; ip += (size_t)M * CPAD;
  int* ovf_n = ip; ip += 6;
  float* wbuf = (float*)ip; ip += 4;
  float* svg  = (float*)ip; ip += F;          // relu-colsum of med (mega path)
  size_t memset_bytes = (size_t)((char*)ip - (char*)d_ws);

  uintptr_t up = ((uintptr_t)ip + 15) & ~(uintptr_t)15;
  int4* ovf = (int4*)up;                       // 6 * OVF_CAP
  uint2* ell1 = (uint2*)(ovf + 6 * OVF_CAP);   // N1 * CAP_A
  uint2* ell2 = ell1 + (size_t)N1 * CAP_A;     // N2 * CAP_A
  unsigned* eg0 = (unsigned*)(ell2 + (size_t)N2 * CAP_A);
  unsigned* eg1 = eg0 + (size_t)P * CAP_G;
  unsigned* eg2 = eg1 + (size_t)P * CAP_G;
  unsigned* eg3 = eg2 + (size_t)M * CAP_G;
  __half* hp = (__half*)(eg3 + (size_t)M * CAP_G);
  __half* pEh   = hp; hp += (size_t)P * F;
  __half* mEh   = hp; hp += (size_t)M * F;
  __half* dEh   = hp; hp += (size_t)DG * F;
  __half* lat1h = hp; hp += (size_t)N1 * F;
  __half* lat2h = hp; hp += (size_t)N2 * F;
  __half* f0h   = hp; hp += (size_t)P * F;
  __half* f1h   = hp; hp += (size_t)P * F;
  __half* f2h   = hp; hp += (size_t)M * F;
  __half* f3h   = hp; hp += (size_t)M * F;
  float* fp = (float*)hp;
  float* lat1f = fp; fp += (size_t)N1 * F;
  float* lat2f = fp; fp += (size_t)N2 * F;
  float* acc1  = fp; fp += (size_t)N1 * F;
  float* acc2  = fp; fp += (size_t)N2 * F;
  float* el    = fp; fp += (size_t)(2 * P + 2 * M) * H;
  float* er    = fp; fp += (size_t)(2 * P + 2 * M) * H;
  float* e0b   = fp; fp += (size_t)P * F;
  float* e1b   = fp; fp += (size_t)P * F;
  float* e2b   = fp; fp += (size_t)M * F;
  float* e3b   = fp; fp += (size_t)M * F;
  float* cbuf  = fp; fp += 256;

  // ---- output layout: (simi_pm, d_gcn, med, m_gcn, patient) ----
  float* out_simi = (float*)d_out;
  float* out_dgcn = out_simi + (size_t)P * M;
  float* out_med  = out_dgcn + (size_t)DG * F;
  float* out_mgcn = out_med  + (size_t)M * F;
  float* out_pat  = out_mgcn + (size_t)M * F;

  // ---- zero counters + barrier state (workspace is poisoned every iter) ----
  hipMemsetAsync(d_ws, 0, memset_bytes, stream);

  // ---- primary path: one persistent kernel with custom grid barriers ----
  static int  s_grid = 0;
  static bool s_coop = true;
  if (s_grid == 0) {
    int nbk = 0;
    if (hipOccupancyMaxActiveBlocksPerMultiprocessor(&nbk, k_mega, 256, 0) != hipSuccess || nbk < 1)
      nbk = 1;
    if (nbk > 8) nbk = 8;
    s_grid = nbk * 256;        // multiple of 64 by construction (quota logic)
  }
  bool done = false;
  if (s_coop) {
    MegaArgs ma;
    ma.a1r = adj1_rows; ma.a1c = adj1_cols; ma.a1v = adj1_vals;
    ma.a2r = adj2_rows; ma.a2c = adj2_cols; ma.a2v = adj2_vals;
    ma.g0s = g0_src; ma.g0d = g0_dst; ma.g1s = g1_src; ma.g1d = g1_dst;
    ma.g2s = g2_src; ma.g2d = g2_dst; ma.g3s = g3_src; ma.g3d = g3_dst;
    ma.pE = pE; ma.mE = mE; ma.dE = dE;
    ma.gat_W = gat_W; ma.gat_al = gat_al; ma.gat_ar = gat_ar; ma.gat_b = gat_b;
    ma.sa_W1 = sa_W1; ma.sa_b1 = sa_b1; ma.sa_W2 = sa_W2;
    ma.out_W = out_W; ma.out_b = out_b;
    ma.bcnt = bar_cnt; ma.bgen = bar_gen;
    ma.cur1 = cur1; ma.cur2 = cur2; ma.cu0 = cu0; ma.cu1 = cu1; ma.cu2 = cu2; ma.cu3 = cu3;
    ma.ovf_n = ovf_n; ma.wbuf = wbuf; ma.svg = svg;
    ma.ovf = ovf; ma.ell1 = ell1; ma.ell2 = ell2;
    ma.eg0 = eg0; ma.eg1 = eg1; ma.eg2 = eg2; ma.eg3 = eg3;
    ma.pEh = pEh; ma.mEh = mEh; ma.dEh = dEh;
    ma.lat1h = lat1h; ma.lat2h = lat2h;
    ma.f0 = f0h; ma.f1 = f1h; ma.f2 = f2h; ma.f3 = f3h;
    ma.lat1f = lat1f; ma.lat2f = lat2f; ma.acc1 = acc1; ma.acc2 = acc2;
    ma.el = el; ma.er = er;
    ma.e0 = e0b; ma.e1 = e1b; ma.e2 = e2b; ma.e3 = e3b;
    ma.out_simi = out_simi; ma.out_dgcn = out_dgcn; ma.out_med = out_med;
    ma.out_mgcn = out_mgcn; ma.out_pat = out_pat;
    void* kargs[] = { &ma };
    // Cooperative launch used ONLY for the co-residency guarantee; the kernel
    // never calls cg::grid.sync() (measured ~100+ us/sync in R1).
    hipError_t e = hipLaunchCooperativeKernel((const void*)k_mega, dim3(s_grid),
                                              dim3(256), kargs, 0, stream);
    if (e == hipSuccess) done = true;
    else s_coop = false;   // fall back permanently
  }

  if (!done) {
    // ---- proven 10-dispatch fallback ----
    int eb = ((HOE + 3) / 4 + 255) / 256;
    k_build<<<eb, 256, 0, stream>>>(adj1_rows, adj1_cols, adj1_vals,
                                    adj2_rows, adj2_cols, adj2_vals,
                                    g0_dst, g0_src, g1_dst, g1_src,
                                    g2_dst, g2_src, g3_dst, g3_src,
                                    cur1, ell1, cur2, ell2,
                                    cu0, eg0, cu1, eg1, cu2, eg2, cu3, eg3,
                                    ovf_n, ovf,
                                    pE, mE, dE, pEh, mEh, dEh);
    int sb = (N1 + N2) / 2;
    k_spmm<1><<<sb, 256, 0, stream>>>(cur1, ell1, cur2, ell2, ovf_n, ovf,
                                      pEh, mEh, dEh, lat1f, lat2f, lat1h, lat2h,
                                      acc1, acc2, out_mgcn, out_dgcn);
    k_spmm<2><<<sb, 256, 0, stream>>>(cur1, ell1, cur2, ell2, ovf_n, ovf,
                                      pEh, mEh, dEh, lat1f, lat2f, lat1h, lat2h,
                                      acc1, acc2, out_mgcn, out_dgcn);
    k_gat_feat_all<<<FEAT_BLOCKS, 256, 0, stream>>>(acc1, acc2, gat_W, gat_al, gat_ar,
                                                    f0h, f1h, f2h, f3h, el, er);
    int ab = (2 * P + 2 * M) / 2;
    k_gat_agg_all<<<ab, 256, 0, stream>>>(cu0, eg0, cu1, eg1, cu2, eg2, cu3, eg3,
                                          ovf_n, ovf, el, er, f0h, f1h, f2h, f3h, gat_b,
                                          e0b, e1b, e2b, e3b);
    k_sem_w_all<<<SEM_BLOCKS, 128, 0, stream>>>(e0b, e1b, e2b, e3b, sa_W1, sa_b1, sa_W2, wbuf);
    k_med_cvec<<<1, 256, 0, stream>>>(e2b, e3b, wbuf, out_W, out_b, out_med, cbuf);
    k_final<<<P / FIN_R, 256, 0, stream>>>(e0b, e1b, wbuf, out_W, cbuf, out_pat, out_simi);
  }
}

// Round 3
// 350.353 us; speedup vs baseline: 2.8895x; 2.8895x over previous
//
#include <hip/hip_runtime.h>
#include <hip/hip_fp16.h>
#include <cmath>
#include <cstdint>

// Problem constants (fixed by the reference).
constexpr int P  = 2000, M = 150, DG = 2000, F = 256, H = 4, DH = 64;
constexpr int N1 = P + M;          // 2150
constexpr int N2 = P + DG;         // 4000
constexpr int E1 = 137600, E2 = 256000, EGP = 64000, EGM = 4800;
constexpr int SA_HID = 128;

// Edge-range offsets for the fused build kernel.
constexpr int HO1 = E1, HO2 = E1 + E2, HO3 = HO2 + EGP, HO4 = HO3 + EGP,
              HO5 = HO4 + EGM, HOE = HO5 + EGM;   // 531200 total edges

// ELL capacities (overflow list guarantees correctness regardless).
constexpr int CAP_A = 160;
constexpr int CAP_G = 96;
constexpr int OVF_CAP = 4096;

// One counter per 64B line (R7: removed same-line atomic serialization).
constexpr int CPAD = 16;

// ---- fp16 helpers -----------------------------------------------------------
__device__ __forceinline__ float4 h4_to_f4(const __half* p) {
  union { ushort4 u4; __half2 h2[2]; } u;
  u.u4 = *(const ushort4*)p;
  float2 lo = __half22float2(u.h2[0]);
  float2 hi = __half22float2(u.h2[1]);
  return make_float4(lo.x, lo.y, hi.x, hi.y);
}
__device__ __forceinline__ void f4_to_h4(__half* p, float4 v) {
  union { ushort4 u4; __half2 h2[2]; } u;
  u.h2[0] = __float22half2_rn(make_float2(v.x, v.y));
  u.h2[1] = __float22half2_rn(make_float2(v.z, v.w));
  *(ushort4*)p = u.u4;
}

// ---------------------------------------------------------------------------
// ELL build (padded counters) + fused fp32->fp16 embed cast.
// ---------------------------------------------------------------------------
constexpr int CAST_CH = (P * F + M * F + DG * F) / 8;   // 8-float chunks

__global__ __launch_bounds__(256) void k_build(
    const int* __restrict__ a1r, const int* __restrict__ a1c, const float* __restrict__ a1v,
    const int* __restrict__ a2r, const int* __restrict__ a2c, const float* __restrict__ a2v,
    const int* __restrict__ d0, const int* __restrict__ s0,
    const int* __restrict__ d1, const int* __restrict__ s1,
    const int* __restrict__ d2, const int* __restrict__ s2,
    const int* __restrict__ d3, const int* __restrict__ s3,
    int* cur1, uint2* ell1, int* cur2, uint2* ell2,
    int* cu0, unsigned* eg0, int* cu1, unsigned* eg1,
    int* cu2, unsigned* eg2, int* cu3, unsigned* eg3,
    int* __restrict__ ovf_n, int4* __restrict__ ovf,
    const float* __restrict__ pEf, const float* __restrict__ mEf,
    const float* __restrict__ dEf,
    __half* __restrict__ pEh, __half* __restrict__ mEh, __half* __restrict__ dEh) {
  int tid = blockIdx.x * 256 + threadIdx.x;
  int T = gridDim.x * 256;
  int seg[4], row[4]; unsigned p0[4], p1[4];
#pragma unroll
  for (int u = 0; u < 4; ++u) {
    int i = tid + u * T;
    seg[u] = -1;
    if (i < HOE) {
      if (i < HO1)      { seg[u] = 0; row[u] = a1r[i]; p0[u] = (unsigned)a1c[i]; p1[u] = __float_as_uint(a1v[i]); }
      else if (i < HO2) { int j = i - HO1; seg[u] = 1; row[u] = a2r[j]; p0[u] = (unsigned)a2c[j]; p1[u] = __float_as_uint(a2v[j]); }
      else if (i < HO3) { int j = i - HO2; seg[u] = 2; row[u] = d0[j]; p0[u] = (unsigned)s0[j]; }
      else if (i < HO4) { int j = i - HO3; seg[u] = 3; row[u] = d1[j]; p0[u] = (unsigned)s1[j]; }
      else if (i < HO5) { int j = i - HO4; seg[u] = 4; row[u] = d2[j]; p0[u] = (unsigned)s2[j]; }
      else              { int j = i - HO5; seg[u] = 5; row[u] = d3[j]; p0[u] = (unsigned)s3[j]; }
    }
  }
#pragma unroll
  for (int u = 0; u < 4; ++u) {
    int r = row[u];
    switch (seg[u]) {
      case 0: { int slot = atomicAdd(&cur1[(size_t)r * CPAD], 1);
        if (slot < CAP_A) ell1[(size_t)r * CAP_A + slot] = make_uint2(p0[u], p1[u]);
        else { int o = atomicAdd(&ovf_n[0], 1); if (o < OVF_CAP) ovf[0 * OVF_CAP + o] = make_int4(r, (int)p0[u], (int)p1[u], 0); } } break;
      case 1: { int slot = atomicAdd(&cur2[(size_t)r * CPAD], 1);
        if (slot < CAP_A) ell2[(size_t)r * CAP_A + slot] = make_uint2(p0[u], p1[u]);
        else { int o = atomicAdd(&ovf_n[1], 1); if (o < OVF_CAP) ovf[1 * OVF_CAP + o] = make_int4(r, (int)p0[u], (int)p1[u], 0); } } break;
      case 2: { int slot = atomicAdd(&cu0[(size_t)r * CPAD], 1);
        if (slot < CAP_G) eg0[(size_t)r * CAP_G + slot] = p0[u];
        else { int o = atomicAdd(&ovf_n[2], 1); if (o < OVF_CAP) ovf[2 * OVF_CAP + o] = make_int4(r, (int)p0[u], 0, 0); } } break;
      case 3: { int slot = atomicAdd(&cu1[(size_t)r * CPAD], 1);
        if (slot < CAP_G) eg1[(size_t)r * CAP_G + slot] = p0[u];
        else { int o = atomicAdd(&ovf_n[3], 1); if (o < OVF_CAP) ovf[3 * OVF_CAP + o] = make_int4(r, (int)p0[u], 0, 0); } } break;
      case 4: { int slot = atomicAdd(&cu2[(size_t)r * CPAD], 1);
        if (slot < CAP_G) eg2[(size_t)r * CAP_G + slot] = p0[u];
        else { int o = atomicAdd(&ovf_n[4], 1); if (o < OVF_CAP) ovf[4 * OVF_CAP + o] = make_int4(r, (int)p0[u], 0, 0); } } break;
      case 5: { int slot = atomicAdd(&cu3[(size_t)r * CPAD], 1);
        if (slot < CAP_G) eg3[(size_t)r * CAP_G + slot] = p0[u];
        else { int o = atomicAdd(&ovf_n[5], 1); if (o < OVF_CAP) ovf[5 * OVF_CAP + o] = make_int4(r, (int)p0[u], 0, 0); } } break;
      default: break;
    }
  }
  // Fused embed cast fp32 -> fp16 (independent streaming work).
  for (int c = tid; c < CAST_CH; c += T) {
    int j = c * 8;
    const float* src; __half* dst;
    if (j < P * F)              { src = pEf + j;               dst = pEh + j; }
    else if (j < P * F + M * F) { src = mEf + (j - P * F);     dst = mEh + (j - P * F); }
    else                        { src = dEf + (j - P*F - M*F); dst = dEh + (j - P*F - M*F); }
    float4 a = *(const float4*)src, b = *(const float4*)(src + 4);
    f4_to_h4(dst, a);
    f4_to_h4(dst + 4, b);
  }
}

// ---------------------------------------------------------------------------
// SPMM: TWO waves per row (edges split by parity, LDS combine), fp16 gathers,
// fp32 accumulate (R9 structure, proven).
// ---------------------------------------------------------------------------
template<int LAYER>
__global__ __launch_bounds__(256) void k_spmm(
    const int* __restrict__ cur1, const uint2* __restrict__ ell1,
    const int* __restrict__ cur2, const uint2* __restrict__ ell2,
    const int* __restrict__ ovf_n, const int4* __restrict__ ovf,
    const __half* __restrict__ pEh, const __half* __restrict__ mEh,
    const __half* __restrict__ dEh,
    float* __restrict__ lat1f, float* __restrict__ lat2f,
    __half* __restrict__ lat1h, __half* __restrict__ lat2h,
    float* __restrict__ acc1, float* __restrict__ acc2,
    float* __restrict__ out_mgcn, float* __restrict__ out_dgcn) {
  int grp = (blockIdx.x * 256 + threadIdx.x) >> 7;   // row-group id
  int lane = threadIdx.x & 63;
  int wh   = (threadIdx.x >> 6) & 1;                 // wave-half within group
  int gl   = threadIdx.x >> 7;                       // group slot in block (0/1)
  bool g2 = grp >= N1;
  int row = g2 ? grp - N1 : grp;
  const uint2* pe = (g2 ? ell2 : ell1) + (size_t)row * CAP_A;
  const __half* latinh = g2 ? lat2h : lat1h;
  const __half* tailEh = g2 ? dEh : mEh;
  int deg = (g2 ? cur2 : cur1)[(size_t)row * CPAD];
  int dn = deg < CAP_A ? deg : CAP_A;
  int fo = lane << 2;
  float4 s = {0.f, 0.f, 0.f, 0.f};
  auto fetch = [&](int c) -> float4 {
    const __half* b;
    if (LAYER == 1) b = (c < P) ? (pEh + (size_t)c * F) : (tailEh + (size_t)(c - P) * F);
    else            b = latinh + (size_t)c * F;
    return h4_to_f4(b + fo);
  };
  int i = wh;
  for (; i + 15 <= dn; i += 16) {    // 8 edges: i, i+2, ..., i+14
    uint2 m[8]; float4 a[8];
#pragma unroll
    for (int u = 0; u < 8; ++u) m[u] = pe[i + 2 * u];
#pragma unroll
    for (int u = 0; u < 8; ++u) a[u] = fetch((int)m[u].x);
#pragma unroll
    for (int u = 0; u < 8; ++u) {
      float v = __uint_as_float(m[u].y);
      s.x += v * a[u].x; s.y += v * a[u].y; s.z += v * a[u].z; s.w += v * a[u].w;
    }
  }
  for (; i < dn; i += 2) {
    uint2 m = pe[i];
    float v = __uint_as_float(m.y);
    float4 a = fetch((int)m.x);
    s.x += v * a.x; s.y += v * a.y; s.z += v * a.z; s.w += v * a.w;
  }
  __shared__ float part[2][F];
  if (wh == 1) *(float4*)&part[gl][fo] = s;
  __syncthreads();
  if (wh == 1) return;
  {
    float4 p = *(const float4*)&part[gl][fo];
    s.x += p.x; s.y += p.y; s.z += p.z; s.w += p.w;
  }
  // Overflow edges (normally zero), wave 0 only.
  {
    int gi = g2 ? 1 : 0;
    int on = ovf_n[gi];
    if (on > 0) {
      const int4* ol = ovf + gi * OVF_CAP;
      for (int k = 0; k < on; ++k) {
        int4 e = ol[k];
        if (e.x == row) {
          float v = __int_as_float(e.z);
          float4 a = fetch(e.y);
          s.x += v * a.x; s.y += v * a.y; s.z += v * a.z; s.w += v * a.w;
        }
      }
    }
  }
  float4 l;
  l.x = s.x > 0.f ? s.x : 0.5f * s.x;
  l.y = s.y > 0.f ? s.y : 0.5f * s.y;
  l.z = s.z > 0.f ? s.z : 0.5f * s.z;
  l.w = s.w > 0.f ? s.w : 0.5f * s.w;
  if (LAYER == 1) {
    *(float4*)((g2 ? lat2f : lat1f) + (size_t)row * F + fo) = l;   // exact own-row
    f4_to_h4((g2 ? lat2h : lat1h) + (size_t)row * F + fo, l);      // gather copy
  } else {
    const float* latf = g2 ? lat2f : lat1f;
    float4 b = *(const float4*)(latf + (size_t)row * F + fo);
    float4 a = {b.x + l.x, b.y + l.y, b.z + l.z, b.w + l.w};
    *(float4*)((g2 ? acc2 : acc1) + (size_t)row * F + fo) = a;
    if (row >= P)
      *(float4*)((g2 ? out_dgcn : out_mgcn) + (size_t)(row - P) * F + fo) = a;
  }
}

// ---------------------------------------------------------------------------
// All 4 GAT feature GEMMs. FR=8 (R8/R9: occupancy beats W-traffic reduction).
// ---------------------------------------------------------------------------
constexpr int FR  = 8;
constexpr int NB0 = (P + FR - 1) / FR;   // 250
constexpr int NB2 = (M + FR - 1) / FR;   // 19
constexpr int FEAT_BLOCKS = 2 * NB0 + 2 * NB2;

__global__ __launch_bounds__(256) void k_gat_feat_all(
    const float* __restrict__ acc1, const float* __restrict__ acc2,
    const float* __restrict__ gat_W, const float* __restrict__ gat_al,
    const float* __restrict__ gat_ar,
    __half* __restrict__ f0, __half* __restrict__ f1,
    __half* __restrict__ f2, __half* __restrict__ f3,
    float* __restrict__ el, float* __restrict__ er) {
  int b = blockIdx.x;
  int g, rb, n; const float* h; __half* fout;
  if (b < NB0)            { g = 0; rb = b;              n = P; h = acc1; fout = f0; }
  else if (b < 2 * NB0)   { g = 1; rb = b - NB0;        n = P; h = acc2; fout = f1; }
  else if (b < 2*NB0+NB2) { g = 2; rb = b - 2 * NB0;    n = M; h = acc1 + (size_t)P * F; fout = f2; }
  else                    { g = 3; rb = b - 2*NB0 - NB2; n = M; h = acc1 + (size_t)P * F; fout = f3; }
  int elo = (g == 0) ? 0 : (g == 1) ? P * H : (g == 2) ? 2 * P * H : (2 * P + M) * H;
  const float* W = gat_W + (size_t)g * F * F;
  __shared__ float hs[FR][F];
  int t = threadIdx.x;
  int r0 = rb * FR;
  for (int q = t; q < FR * 64; q += 256) {
    int r = q >> 6, ln = q & 63;
    int row = r0 + r;
    float4 v = {0.f, 0.f, 0.f, 0.f};
    if (row < n) v = *(const float4*)(h + (size_t)row * F + (ln << 2));
    *(float4*)&hs[r][ln << 2] = v;
  }
  __syncthreads();
  float acc[FR];
#pragma unroll
  for (int r = 0; r < FR; ++r) acc[r] = 0.f;
  for (int k = 0; k < F; k += 4) {
    float w0 = W[(size_t)k * F + t],       w1 = W[(size_t)(k + 1) * F + t],
          w2 = W[(size_t)(k + 2) * F + t], w3 = W[(size_t)(k + 3) * F + t];
#pragma unroll
    for (int r = 0; r < FR; ++r) {
      float4 h4 = *(const float4*)&hs[r][k];
      acc[r] += h4.x * w0 + h4.y * w1 + h4.z * w2 + h4.w * w3;
    }
  }
  int head = t >> 6, d = t & 63;           // one wave == one head
  float av = gat_al[g * H * DH + head * DH + d];
  float rv = gat_ar[g * H * DH + head * DH + d];
#pragma unroll
  for (int r = 0; r < FR; ++r) {
    int row = r0 + r;
    if (row < n) {
      fout[(size_t)row * F + t] = __float2half_rn(acc[r]);
      float cl = acc[r] * av, cr = acc[r] * rv;
      for (int o = 32; o > 0; o >>= 1) {
        cl += __shfl_down(cl, o, 64);
        cr += __shfl_down(cr, o, 64);
      }
      if (d == 0) { el[elo + row * H + head] = cl; er[elo + row * H + head] = cr; }
    }
  }
}

// ---------------------------------------------------------------------------
// All 4 GAT aggregations (2 waves per dst-row, edge-parity split) WITH the
// semantic-attention row contribution fused in (R3): after wave 0 finalizes
// the ELU'd output row v, both waves of the group compute
// tanh(v @ W1 + b1) @ W2 and atomicAdd one scalar into wbuf[g].
// This removes the separate k_sem_w_all dispatch.
// ---------------------------------------------------------------------------
__global__ __launch_bounds__(256) void k_gat_agg_sem(
    const int* __restrict__ cu0, const unsigned* __restrict__ eg0,
    const int* __restrict__ cu1, const unsigned* __restrict__ eg1,
    const int* __restrict__ cu2, const unsigned* __restrict__ eg2,
    const int* __restrict__ cu3, const unsigned* __restrict__ eg3,
    const int* __restrict__ ovf_n, const int4* __restrict__ ovf,
    const float* __restrict__ el, const float* __restrict__ er,
    const __half* __restrict__ f0, const __half* __restrict__ f1,
    const __half* __restrict__ f2, const __half* __restrict__ f3,
    const float* __restrict__ gat_b,
    const float* __restrict__ W1, const float* __restrict__ b1,
    const float* __restrict__ W2, float* __restrict__ wbuf,
    float* __restrict__ e0, float* __restrict__ e1,
    float* __restrict__ e2, float* __restrict__ e3) {
  int tid  = threadIdx.x;
  int grp  = (blockIdx.x * 256 + tid) >> 7;
  int lane = tid & 63;
  int wh   = (tid >> 6) & 1;
  int gl   = tid >> 7;
  int g, row; const int* cu; const unsigned* eg; const __half* feat; float* out; int elo;
  if (grp < P)            { g = 0; row = grp;             cu = cu0; eg = eg0; feat = f0; out = e0; elo = 0; }
  else if (grp < 2 * P)   { g = 1; row = grp - P;         cu = cu1; eg = eg1; feat = f1; out = e1; elo = P * H; }
  else if (grp < 2*P + M) { g = 2; row = grp - 2 * P;     cu = cu2; eg = eg2; feat = f2; out = e2; elo = 2 * P * H; }
  else                    { g = 3; row = grp - 2 * P - M; cu = cu3; eg = eg3; feat = f3; out = e3; elo = (2 * P + M) * H; }
  int head = lane >> 4;
  int fo = lane << 2;
  const float* elb = el + elo;
  float erv = er[elo + row * H + head];
  int deg = cu[(size_t)row * CPAD];
  int dn = deg < CAP_G ? deg : CAP_G;
  const unsigned* ps = eg + (size_t)row * CAP_G;
  int on = ovf_n[2 + g];
  const int4* ol = ovf + (2 + g) * OVF_CAP;
  // ---- pass 1: max over this wave's parity edges ----
  float mx = -3.4e38f;
  int i = wh;
  for (; i + 7 <= dn; i += 8) {     // 4 edges: i, i+2, i+4, i+6
    int s0 = (int)ps[i], s1 = (int)ps[i + 2], s2 = (int)ps[i + 4], s3 = (int)ps[i + 6];
    float a = elb[s0 * H + head] + erv, b = elb[s1 * H + head] + erv,
          c = elb[s2 * H + head] + erv, d = elb[s3 * H + head] + erv;
    a = a > 0.f ? a : 0.2f * a; b = b > 0.f ? b : 0.2f * b;
    c = c > 0.f ? c : 0.2f * c; d = d > 0.f ? d : 0.2f * d;
    mx = fmaxf(mx, fmaxf(fmaxf(a, b), fmaxf(c, d)));
  }
  for (; i < dn; i += 2) {
    float a = elb[(int)ps[i] * H + head] + erv;
    a = a > 0.f ? a : 0.2f * a;
    mx = fmaxf(mx, a);
  }
  if (wh == 0 && on > 0) {
    for (int k = 0; k < on; ++k) {
      int4 e = ol[k];
      if (e.x == row) {
        float a = elb[e.y * H + head] + erv;
        a = a > 0.f ? a : 0.2f * a;
        mx = fmaxf(mx, a);
      }
    }
  }
  __shared__ float mxs[2][2][64];
  mxs[gl][wh][lane] = mx;
  __syncthreads();
  mx = fmaxf(mxs[gl][0][lane], mxs[gl][1][lane]);
  // ---- pass 2: exp-sum + weighted aggregation over parity edges ----
  float ssum = 0.f;
  float4 acc = {0.f, 0.f, 0.f, 0.f};
  i = wh;
  for (; i + 3 <= dn; i += 4) {     // 2 edges: i, i+2
    int s0 = (int)ps[i], s1 = (int)ps[i + 2];
    float a = elb[s0 * H + head] + erv; a = a > 0.f ? a : 0.2f * a;
    float b = elb[s1 * H + head] + erv; b = b > 0.f ? b : 0.2f * b;
    float x0 = expf(a - mx), x1 = expf(b - mx);
    float4 q0 = h4_to_f4(feat + (size_t)s0 * F + fo);
    float4 q1 = h4_to_f4(feat + (size_t)s1 * F + fo);
    ssum += x0 + x1;
    acc.x += x0 * q0.x + x1 * q1.x;
    acc.y += x0 * q0.y + x1 * q1.y;
    acc.z += x0 * q0.z + x1 * q1.z;
    acc.w += x0 * q0.w + x1 * q1.w;
  }
  for (; i < dn; i += 2) {
    int s0 = (int)ps[i];
    float a = elb[s0 * H + head] + erv; a = a > 0.f ? a : 0.2f * a;
    float x0 = expf(a - mx);
    float4 q0 = h4_to_f4(feat + (size_t)s0 * F + fo);
    ssum += x0;
    acc.x += x0 * q0.x; acc.y += x0 * q0.y; acc.z += x0 * q0.z; acc.w += x0 * q0.w;
  }
  __shared__ float4 pacc[2][64];
  __shared__ float  pss[2][64];
  __shared__ float  zrow[2][F];
  __shared__ float  pp[4];
  if (wh == 1) { pacc[gl][lane] = acc; pss[gl][lane] = ssum; }
  __syncthreads();
  if (wh == 0) {
    float4 pa = pacc[gl][lane];
    acc.x += pa.x; acc.y += pa.y; acc.z += pa.z; acc.w += pa.w;
    ssum += pss[gl][lane];
    if (on > 0) {
      for (int k = 0; k < on; ++k) {
        int4 e = ol[k];
        if (e.x == row) {
          float a = elb[e.y * H + head] + erv; a = a > 0.f ? a : 0.2f * a;
          float x0 = expf(a - mx);
          float4 q0 = h4_to_f4(feat + (size_t)e.y * F + fo);
          ssum += x0;
          acc.x += x0 * q0.x; acc.y += x0 * q0.y; acc.z += x0 * q0.z; acc.w += x0 * q0.w;
        }
      }
    }
    float inv = 1.f / (ssum + 1e-9f);
    const float* bb = gat_b + g * F + fo;
    float4 v = {acc.x * inv + bb[0], acc.y * inv + bb[1],
                acc.z * inv + bb[2], acc.w * inv + bb[3]};
    v.x = v.x > 0.f ? v.x : expm1f(v.x);
    v.y = v.y > 0.f ? v.y : expm1f(v.y);
    v.z = v.z > 0.f ? v.z : expm1f(v.z);
    v.w = v.w > 0.f ? v.w : expm1f(v.w);
    *(float4*)(out + (size_t)row * F + fo) = v;
    *(float4*)&zrow[gl][fo] = v;
  }
  __syncthreads();
  // ---- fused semantic-attention contribution: 128 threads, 1 hidden/thread ---
  {
    int hh = tid & 127;                       // hidden unit index
    float hid = b1[hh];
    const float* z = zrow[gl];
    for (int k = 0; k < F; k += 4) {
      hid += z[k]     * W1[(size_t)k       * SA_HID + hh]
           + z[k + 1] * W1[(size_t)(k + 1) * SA_HID + hh]
           + z[k + 2] * W1[(size_t)(k + 2) * SA_HID + hh]
           + z[k + 3] * W1[(size_t)(k + 3) * SA_HID + hh];
    }
    float val = tanhf(hid) * W2[hh];
    for (int o = 32; o > 0; o >>= 1) val += __shfl_down(val, o, 64);
    if (lane == 0) pp[tid >> 6] = val;
    __syncthreads();
    if ((tid & 127) == 0) atomicAdd(&wbuf[g], pp[gl * 2] + pp[gl * 2 + 1]);
  }
}

// ---------------------------------------------------------------------------
// Final (R3-fused): per block — recompute med combine + relu col-sum sv,
// c-vector, then patient beta-combine + simi GEMM for FIN_R rows.
// Block 0 additionally writes out_med. Removes k_med_cvec entirely.
// ---------------------------------------------------------------------------
constexpr int FIN_R = 8;   // P % FIN_R == 0 -> 250 blocks
__global__ __launch_bounds__(256) void k_final_all(
    const float* __restrict__ e0, const float* __restrict__ e1,
    const float* __restrict__ e2, const float* __restrict__ e3,
    const float* __restrict__ w, const float* __restrict__ outW,
    const float* __restrict__ outb,
    float* __restrict__ out_med, float* __restrict__ out_pat,
    float* __restrict__ simi) {
  int t = threadIdx.x;
  // betas
  float mm0 = w[2] * (1.f / M), mm1 = w[3] * (1.f / M);
  float mmx = fmaxf(mm0, mm1);
  float bm0 = expf(mm0 - mmx), bm1 = expf(mm1 - mmx);
  float msc = 1.f / (bm0 + bm1);
  bm0 *= msc; bm1 *= msc;
  float pm0 = w[0] * (1.f / P), pm1 = w[1] * (1.f / P);
  float pmx = fmaxf(pm0, pm1);
  float bp0 = expf(pm0 - pmx), bp1 = expf(pm1 - pmx);
  float psc = 1.f / (bp0 + bp1);
  bp0 *= psc; bp1 *= psc;
  // ---- med combine + relu col-sum (every block; block 0 writes out_med) ----
  constexpr int MED4 = M * F / 4;   // 9600
  float4 rs = {0.f, 0.f, 0.f, 0.f};
  bool wr_med = (blockIdx.x == 0);
  for (int j = t; j < MED4; j += 256) {
    float4 u0 = ((const float4*)e2)[j], u1 = ((const float4*)e3)[j];
    float4 r = {bm0 * u0.x + bm1 * u1.x, bm0 * u0.y + bm1 * u1.y,
                bm0 * u0.z + bm1 * u1.z, bm0 * u0.w + bm1 * u1.w};
    if (wr_med) ((float4*)out_med)[j] = r;
    rs.x += r.x > 0.f ? r.x : 0.f;
    rs.y += r.y > 0.f ? r.y : 0.f;
    rs.z += r.z > 0.f ? r.z : 0.f;
    rs.w += r.w > 0.f ? r.w : 0.f;
  }
  __shared__ float4 sv4[4][64];
  sv4[t >> 6][t & 63] = rs;
  __syncthreads();
  __shared__ float sv[F];
  if (t < 64) {
    float4 a = sv4[0][t], b = sv4[1][t], c = sv4[2][t], d = sv4[3][t];
    sv[t * 4 + 0] = a.x + b.x + c.x + d.x;
    sv[t * 4 + 1] = a.y + b.y + c.y + d.y;
    sv[t * 4 + 2] = a.z + b.z + c.z + d.z;
    sv[t * 4 + 3] = a.w + b.w + c.w + d.w;
  }
  __syncthreads();
  // ---- c-vector (per thread t < M), kept in register ----
  float cv = 0.f;
  if (t < M) {
    float cc = (float)M * outb[t];
    for (int f = 0; f < F; f += 4) {
      cc += sv[f]     * outW[(size_t)(F + f) * M + t]
          + sv[f + 1] * outW[(size_t)(F + f + 1) * M + t]
          + sv[f + 2] * outW[(size_t)(F + f + 2) * M + t]
          + sv[f + 3] * outW[(size_t)(F + f + 3) * M + t];
    }
    cv = cc;
  }
  // ---- patient combine + simi GEMM for FIN_R rows ----
  __shared__ float psh[FIN_R][F];
  int r0 = blockIdx.x * FIN_R;
  for (int q = t; q < FIN_R * 64; q += 256) {
    int r = q >> 6, ln = q & 63;
    size_t off = (size_t)(r0 + r) * F + (ln << 2);
    float4 u0 = *(const float4*)(e0 + off), u1 = *(const float4*)(e1 + off);
    float4 v = {bp0 * u0.x + bp1 * u1.x, bp0 * u0.y + bp1 * u1.y,
                bp0 * u0.z + bp1 * u1.z, bp0 * u0.w + bp1 * u1.w};
    *(float4*)(out_pat + off) = v;
    v.x = v.x > 0.f ? v.x : 0.f; v.y = v.y > 0.f ? v.y : 0.f;
    v.z = v.z > 0.f ? v.z : 0.f; v.w = v.w > 0.f ? v.w : 0.f;
    *(float4*)&psh[r][ln << 2] = v;
  }
  __syncthreads();
  if (t < M) {
    float acc[FIN_R];
#pragma unroll
    for (int r = 0; r < FIN_R; ++r) acc[r] = 0.f;
    for (int f = 0; f < F; f += 4) {
      float w0 = outW[(size_t)f * M + t],       w1 = outW[(size_t)(f + 1) * M + t],
            w2 = outW[(size_t)(f + 2) * M + t], w3 = outW[(size_t)(f + 3) * M + t];
#pragma unroll
      for (int r = 0; r < FIN_R; ++r) {
        float4 p4 = *(const float4*)&psh[r][f];
        acc[r] += p4.x * w0 + p4.y * w1 + p4.z * w2 + p4.w * w3;
      }
    }
#pragma unroll
    for (int r = 0; r < FIN_R; ++r)
      simi[(size_t)(r0 + r) * M + t] = (float)M * acc[r] + cv;
  }
}

// ---------------------------------------------------------------------------
extern "C" void kernel_launch(void* const* d_in, const int* in_sizes, int n_in,
                              void* d_out, int out_size, void* d_ws, size_t ws_size,
                              hipStream_t stream) {
  const int*   adj1_rows = (const int*)d_in[0];
  const int*   adj1_cols = (const int*)d_in[1];
  const float* adj1_vals = (const float*)d_in[2];
  const int*   adj2_rows = (const int*)d_in[3];
  const int*   adj2_cols = (const int*)d_in[4];
  const float* adj2_vals = (const float*)d_in[5];
  const int*   g0_src = (const int*)d_in[6];
  const int*   g0_dst = (const int*)d_in[7];
  const int*   g1_src = (const int*)d_in[8];
  const int*   g1_dst = (const int*)d_in[9];
  const int*   g2_src = (const int*)d_in[10];
  const int*   g2_dst = (const int*)d_in[11];
  const int*   g3_src = (const int*)d_in[12];
  const int*   g3_dst = (const int*)d_in[13];
  // d_in[14] = keepRate (unused, == 1)
  const float* pE     = (const float*)d_in[15];
  const float* mE     = (const float*)d_in[16];
  const float* dE     = (const float*)d_in[17];
  const float* gat_W  = (const float*)d_in[18];
  const float* gat_al = (const float*)d_in[19];
  const float* gat_ar = (const float*)d_in[20];
  const float* gat_b  = (const float*)d_in[21];
  const float* sa_W1  = (const float*)d_in[22];
  const float* sa_b1  = (const float*)d_in[23];
  const float* sa_W2  = (const float*)d_in[24];
  const float* out_W  = (const float*)d_in[25];
  const float* out_b  = (const float*)d_in[26];

  // ---- workspace layout: [zeroed (padded counters) | ELL | fp16 | fp32] ----
  int* ip = (int*)d_ws;
  int* cur1 = ip; ip += (size_t)N1 * CPAD;
  int* cur2 = ip; ip += (size_t)N2 * CPAD;
  int* cu0  = ip; ip += (size_t)P * CPAD;
  int* cu1  = ip; ip += (size_t)P * CPAD;
  int* cu2  = ip; ip += (size_t)M * CPAD;
  int* cu3  = ip; ip += (size_t)M * CPAD;
  int* ovf_n = ip; ip += 6;
  float* wbuf = (float*)ip; ip += 4;
  size_t memset_bytes = (size_t)((char*)ip - (char*)d_ws);

  uintptr_t up = ((uintptr_t)ip + 15) & ~(uintptr_t)15;
  int4* ovf = (int4*)up;                       // 6 * OVF_CAP
  uint2* ell1 = (uint2*)(ovf + 6 * OVF_CAP);   // N1 * CAP_A
  uint2* ell2 = ell1 + (size_t)N1 * CAP_A;     // N2 * CAP_A
  unsigned* eg0 = (unsigned*)(ell2 + (size_t)N2 * CAP_A);
  unsigned* eg1 = eg0 + (size_t)P * CAP_G;
  unsigned* eg2 = eg1 + (size_t)P * CAP_G;
  unsigned* eg3 = eg2 + (size_t)M * CAP_G;
  // fp16 region (16B-aligned by construction)
  __half* hp = (__half*)(eg3 + (size_t)M * CAP_G);
  __half* pEh   = hp; hp += (size_t)P * F;
  __half* mEh   = hp; hp += (size_t)M * F;
  __half* dEh   = hp; hp += (size_t)DG * F;
  __half* lat1h = hp; hp += (size_t)N1 * F;
  __half* lat2h = hp; hp += (size_t)N2 * F;
  __half* f0h   = hp; hp += (size_t)P * F;
  __half* f1h   = hp; hp += (size_t)P * F;
  __half* f2h   = hp; hp += (size_t)M * F;
  __half* f3h   = hp; hp += (size_t)M * F;
  float* fp = (float*)hp;
  float* lat1f = fp; fp += (size_t)N1 * F;
  float* lat2f = fp; fp += (size_t)N2 * F;
  float* acc1  = fp; fp += (size_t)N1 * F;
  float* acc2  = fp; fp += (size_t)N2 * F;
  float* el    = fp; fp += (size_t)(2 * P + 2 * M) * H;
  float* er    = fp; fp += (size_t)(2 * P + 2 * M) * H;
  float* e0b   = fp; fp += (size_t)P * F;
  float* e1b   = fp; fp += (size_t)P * F;
  float* e2b   = fp; fp += (size_t)M * F;
  float* e3b   = fp; fp += (size_t)M * F;

  // ---- output layout: (simi_pm, d_gcn, med, m_gcn, patient) ----
  float* out_simi = (float*)d_out;               // P*M
  float* out_dgcn = out_simi + (size_t)P * M;    // DG*F
  float* out_med  = out_dgcn + (size_t)DG * F;   // M*F
  float* out_mgcn = out_med  + (size_t)M * F;    // M*F
  float* out_pat  = out_mgcn + (size_t)M * F;    // P*F

  // ---- zero padded counters (~540 KB) ----
  hipMemsetAsync(d_ws, 0, memset_bytes, stream);

  // ---- ELL build + fused fp16 embed cast: ONE dispatch ----
  int eb = ((HOE + 3) / 4 + 255) / 256;
  k_build<<<eb, 256, 0, stream>>>(adj1_rows, adj1_cols, adj1_vals,
                                  adj2_rows, adj2_cols, adj2_vals,
                                  g0_dst, g0_src, g1_dst, g1_src,
                                  g2_dst, g2_src, g3_dst, g3_src,
                                  cur1, ell1, cur2, ell2,
                                  cu0, eg0, cu1, eg1, cu2, eg2, cu3, eg3,
                                  ovf_n, ovf,
                                  pE, mE, dE, pEh, mEh, dEh);

  // ---- GNN: 2 layers, 2 waves per row (edge-parity split) ----
  int sb = (N1 + N2) / 2;
  k_spmm<1><<<sb, 256, 0, stream>>>(cur1, ell1, cur2, ell2, ovf_n, ovf,
                                    pEh, mEh, dEh, lat1f, lat2f, lat1h, lat2h,
                                    acc1, acc2, out_mgcn, out_dgcn);
  k_spmm<2><<<sb, 256, 0, stream>>>(cur1, ell1, cur2, ell2, ovf_n, ovf,
                                    pEh, mEh, dEh, lat1f, lat2f, lat1h, lat2h,
                                    acc1, acc2, out_mgcn, out_dgcn);

  // ---- 4 GATs: scalar feature GEMM + 2-wave-split aggregation (+sem) ----
  k_gat_feat_all<<<FEAT_BLOCKS, 256, 0, stream>>>(acc1, acc2, gat_W, gat_al, gat_ar,
                                                  f0h, f1h, f2h, f3h, el, er);
  int ab = (2 * P + 2 * M) / 2;   // 4300 groups * 128 threads / 256
  k_gat_agg_sem<<<ab, 256, 0, stream>>>(cu0, eg0, cu1, eg1, cu2, eg2, cu3, eg3,
                                        ovf_n, ovf, el, er, f0h, f1h, f2h, f3h, gat_b,
                                        sa_W1, sa_b1, sa_W2, wbuf,
                                        e0b, e1b, e2b, e3b);

  // ---- final: med+cvec recompute-per-block + patient combine + simi ----
  k_final_all<<<P / FIN_R, 256, 0, stream>>>(e0b, e1b, e2b, e3b, wbuf, out_W, out_b,
                                             out_med, out_pat, out_simi);
}

// Round 4
// 309.350 us; speedup vs baseline: 3.2725x; 1.1325x over previous
//
#include <hip/hip_runtime.h>
#include <hip/hip_fp16.h>
#include <cmath>
#include <cstdint>

// Problem constants (fixed by the reference).
constexpr int P  = 2000, M = 150, DG = 2000, F = 256, H = 4, DH = 64;
constexpr int N1 = P + M;          // 2150
constexpr int N2 = P + DG;         // 4000
constexpr int E1 = 137600, E2 = 256000, EGP = 64000, EGM = 4800;
constexpr int SA_HID = 128;

// Edge-range offsets for the fused build kernel.
constexpr int HO1 = E1, HO2 = E1 + E2, HO3 = HO2 + EGP, HO4 = HO3 + EGP,
              HO5 = HO4 + EGM, HOE = HO5 + EGM;   // 531200 total edges

// ELL capacities (overflow list guarantees correctness regardless).
constexpr int CAP_A = 160;
constexpr int CAP_G = 96;
constexpr int OVF_CAP = 4096;

// One counter per 64B line (R7: removed same-line atomic serialization).
constexpr int CPAD = 16;

// ---- fp16 helpers -----------------------------------------------------------
__device__ __forceinline__ float4 h4_to_f4(const __half* p) {
  union { ushort4 u4; __half2 h2[2]; } u;
  u.u4 = *(const ushort4*)p;
  float2 lo = __half22float2(u.h2[0]);
  float2 hi = __half22float2(u.h2[1]);
  return make_float4(lo.x, lo.y, hi.x, hi.y);
}
__device__ __forceinline__ void f4_to_h4(__half* p, float4 v) {
  union { ushort4 u4; __half2 h2[2]; } u;
  u.h2[0] = __float22half2_rn(make_float2(v.x, v.y));
  u.h2[1] = __float22half2_rn(make_float2(v.z, v.w));
  *(ushort4*)p = u.u4;
}

// ---------------------------------------------------------------------------
// ELL build (padded counters) + fused fp32->fp16 embed cast.
// ---------------------------------------------------------------------------
constexpr int CAST_CH = (P * F + M * F + DG * F) / 8;   // 8-float chunks

__global__ __launch_bounds__(256) void k_build(
    const int* __restrict__ a1r, const int* __restrict__ a1c, const float* __restrict__ a1v,
    const int* __restrict__ a2r, const int* __restrict__ a2c, const float* __restrict__ a2v,
    const int* __restrict__ d0, const int* __restrict__ s0,
    const int* __restrict__ d1, const int* __restrict__ s1,
    const int* __restrict__ d2, const int* __restrict__ s2,
    const int* __restrict__ d3, const int* __restrict__ s3,
    int* cur1, uint2* ell1, int* cur2, uint2* ell2,
    int* cu0, unsigned* eg0, int* cu1, unsigned* eg1,
    int* cu2, unsigned* eg2, int* cu3, unsigned* eg3,
    int* __restrict__ ovf_n, int4* __restrict__ ovf,
    const float* __restrict__ pEf, const float* __restrict__ mEf,
    const float* __restrict__ dEf,
    __half* __restrict__ pEh, __half* __restrict__ mEh, __half* __restrict__ dEh) {
  int tid = blockIdx.x * 256 + threadIdx.x;
  int T = gridDim.x * 256;
  int seg[4], row[4]; unsigned p0[4], p1[4];
#pragma unroll
  for (int u = 0; u < 4; ++u) {
    int i = tid + u * T;
    seg[u] = -1;
    if (i < HOE) {
      if (i < HO1)      { seg[u] = 0; row[u] = a1r[i]; p0[u] = (unsigned)a1c[i]; p1[u] = __float_as_uint(a1v[i]); }
      else if (i < HO2) { int j = i - HO1; seg[u] = 1; row[u] = a2r[j]; p0[u] = (unsigned)a2c[j]; p1[u] = __float_as_uint(a2v[j]); }
      else if (i < HO3) { int j = i - HO2; seg[u] = 2; row[u] = d0[j]; p0[u] = (unsigned)s0[j]; }
      else if (i < HO4) { int j = i - HO3; seg[u] = 3; row[u] = d1[j]; p0[u] = (unsigned)s1[j]; }
      else if (i < HO5) { int j = i - HO4; seg[u] = 4; row[u] = d2[j]; p0[u] = (unsigned)s2[j]; }
      else              { int j = i - HO5; seg[u] = 5; row[u] = d3[j]; p0[u] = (unsigned)s3[j]; }
    }
  }
#pragma unroll
  for (int u = 0; u < 4; ++u) {
    int r = row[u];
    switch (seg[u]) {
      case 0: { int slot = atomicAdd(&cur1[(size_t)r * CPAD], 1);
        if (slot < CAP_A) ell1[(size_t)r * CAP_A + slot] = make_uint2(p0[u], p1[u]);
        else { int o = atomicAdd(&ovf_n[0], 1); if (o < OVF_CAP) ovf[0 * OVF_CAP + o] = make_int4(r, (int)p0[u], (int)p1[u], 0); } } break;
      case 1: { int slot = atomicAdd(&cur2[(size_t)r * CPAD], 1);
        if (slot < CAP_A) ell2[(size_t)r * CAP_A + slot] = make_uint2(p0[u], p1[u]);
        else { int o = atomicAdd(&ovf_n[1], 1); if (o < OVF_CAP) ovf[1 * OVF_CAP + o] = make_int4(r, (int)p0[u], (int)p1[u], 0); } } break;
      case 2: { int slot = atomicAdd(&cu0[(size_t)r * CPAD], 1);
        if (slot < CAP_G) eg0[(size_t)r * CAP_G + slot] = p0[u];
        else { int o = atomicAdd(&ovf_n[2], 1); if (o < OVF_CAP) ovf[2 * OVF_CAP + o] = make_int4(r, (int)p0[u], 0, 0); } } break;
      case 3: { int slot = atomicAdd(&cu1[(size_t)r * CPAD], 1);
        if (slot < CAP_G) eg1[(size_t)r * CAP_G + slot] = p0[u];
        else { int o = atomicAdd(&ovf_n[3], 1); if (o < OVF_CAP) ovf[3 * OVF_CAP + o] = make_int4(r, (int)p0[u], 0, 0); } } break;
      case 4: { int slot = atomicAdd(&cu2[(size_t)r * CPAD], 1);
        if (slot < CAP_G) eg2[(size_t)r * CAP_G + slot] = p0[u];
        else { int o = atomicAdd(&ovf_n[4], 1); if (o < OVF_CAP) ovf[4 * OVF_CAP + o] = make_int4(r, (int)p0[u], 0, 0); } } break;
      case 5: { int slot = atomicAdd(&cu3[(size_t)r * CPAD], 1);
        if (slot < CAP_G) eg3[(size_t)r * CAP_G + slot] = p0[u];
        else { int o = atomicAdd(&ovf_n[5], 1); if (o < OVF_CAP) ovf[5 * OVF_CAP + o] = make_int4(r, (int)p0[u], 0, 0); } } break;
      default: break;
    }
  }
  // Fused embed cast fp32 -> fp16 (independent streaming work).
  for (int c = tid; c < CAST_CH; c += T) {
    int j = c * 8;
    const float* src; __half* dst;
    if (j < P * F)              { src = pEf + j;               dst = pEh + j; }
    else if (j < P * F + M * F) { src = mEf + (j - P * F);     dst = mEh + (j - P * F); }
    else                        { src = dEf + (j - P*F - M*F); dst = dEh + (j - P*F - M*F); }
    float4 a = *(const float4*)src, b = *(const float4*)(src + 4);
    f4_to_h4(dst, a);
    f4_to_h4(dst + 4, b);
  }
}

// ---------------------------------------------------------------------------
// SPMM: TWO waves per row (edges split by parity, LDS combine), fp16 gathers,
// fp32 accumulate (R9 structure, proven).
// ---------------------------------------------------------------------------
template<int LAYER>
__global__ __launch_bounds__(256) void k_spmm(
    const int* __restrict__ cur1, const uint2* __restrict__ ell1,
    const int* __restrict__ cur2, const uint2* __restrict__ ell2,
    const int* __restrict__ ovf_n, const int4* __restrict__ ovf,
    const __half* __restrict__ pEh, const __half* __restrict__ mEh,
    const __half* __restrict__ dEh,
    float* __restrict__ lat1f, float* __restrict__ lat2f,
    __half* __restrict__ lat1h, __half* __restrict__ lat2h,
    float* __restrict__ acc1, float* __restrict__ acc2,
    float* __restrict__ out_mgcn, float* __restrict__ out_dgcn) {
  int grp = (blockIdx.x * 256 + threadIdx.x) >> 7;   // row-group id
  int lane = threadIdx.x & 63;
  int wh   = (threadIdx.x >> 6) & 1;                 // wave-half within group
  int gl   = threadIdx.x >> 7;                       // group slot in block (0/1)
  bool g2 = grp >= N1;
  int row = g2 ? grp - N1 : grp;
  const uint2* pe = (g2 ? ell2 : ell1) + (size_t)row * CAP_A;
  const __half* latinh = g2 ? lat2h : lat1h;
  const __half* tailEh = g2 ? dEh : mEh;
  int deg = (g2 ? cur2 : cur1)[(size_t)row * CPAD];
  int dn = deg < CAP_A ? deg : CAP_A;
  int fo = lane << 2;
  float4 s = {0.f, 0.f, 0.f, 0.f};
  auto fetch = [&](int c) -> float4 {
    const __half* b;
    if (LAYER == 1) b = (c < P) ? (pEh + (size_t)c * F) : (tailEh + (size_t)(c - P) * F);
    else            b = latinh + (size_t)c * F;
    return h4_to_f4(b + fo);
  };
  int i = wh;
  for (; i + 15 <= dn; i += 16) {    // 8 edges: i, i+2, ..., i+14
    uint2 m[8]; float4 a[8];
#pragma unroll
    for (int u = 0; u < 8; ++u) m[u] = pe[i + 2 * u];
#pragma unroll
    for (int u = 0; u < 8; ++u) a[u] = fetch((int)m[u].x);
#pragma unroll
    for (int u = 0; u < 8; ++u) {
      float v = __uint_as_float(m[u].y);
      s.x += v * a[u].x; s.y += v * a[u].y; s.z += v * a[u].z; s.w += v * a[u].w;
    }
  }
  for (; i < dn; i += 2) {
    uint2 m = pe[i];
    float v = __uint_as_float(m.y);
    float4 a = fetch((int)m.x);
    s.x += v * a.x; s.y += v * a.y; s.z += v * a.z; s.w += v * a.w;
  }
  __shared__ float part[2][F];
  if (wh == 1) *(float4*)&part[gl][fo] = s;
  __syncthreads();
  if (wh == 1) return;
  {
    float4 p = *(const float4*)&part[gl][fo];
    s.x += p.x; s.y += p.y; s.z += p.z; s.w += p.w;
  }
  // Overflow edges (normally zero), wave 0 only.
  {
    int gi = g2 ? 1 : 0;
    int on = ovf_n[gi];
    if (on > 0) {
      const int4* ol = ovf + gi * OVF_CAP;
      for (int k = 0; k < on; ++k) {
        int4 e = ol[k];
        if (e.x == row) {
          float v = __int_as_float(e.z);
          float4 a = fetch(e.y);
          s.x += v * a.x; s.y += v * a.y; s.z += v * a.z; s.w += v * a.w;
        }
      }
    }
  }
  float4 l;
  l.x = s.x > 0.f ? s.x : 0.5f * s.x;
  l.y = s.y > 0.f ? s.y : 0.5f * s.y;
  l.z = s.z > 0.f ? s.z : 0.5f * s.z;
  l.w = s.w > 0.f ? s.w : 0.5f * s.w;
  if (LAYER == 1) {
    *(float4*)((g2 ? lat2f : lat1f) + (size_t)row * F + fo) = l;   // exact own-row
    f4_to_h4((g2 ? lat2h : lat1h) + (size_t)row * F + fo, l);      // gather copy
  } else {
    const float* latf = g2 ? lat2f : lat1f;
    float4 b = *(const float4*)(latf + (size_t)row * F + fo);
    float4 a = {b.x + l.x, b.y + l.y, b.z + l.z, b.w + l.w};
    *(float4*)((g2 ? acc2 : acc1) + (size_t)row * F + fo) = a;
    if (row >= P)
      *(float4*)((g2 ? out_dgcn : out_mgcn) + (size_t)(row - P) * F + fo) = a;
  }
}

// ---------------------------------------------------------------------------
// All 4 GAT feature GEMMs. FR=8 (R8/R9: occupancy beats W-traffic reduction).
// ---------------------------------------------------------------------------
constexpr int FR  = 8;
constexpr int NB0 = (P + FR - 1) / FR;   // 250
constexpr int NB2 = (M + FR - 1) / FR;   // 19
constexpr int FEAT_BLOCKS = 2 * NB0 + 2 * NB2;

__global__ __launch_bounds__(256) void k_gat_feat_all(
    const float* __restrict__ acc1, const float* __restrict__ acc2,
    const float* __restrict__ gat_W, const float* __restrict__ gat_al,
    const float* __restrict__ gat_ar,
    __half* __restrict__ f0, __half* __restrict__ f1,
    __half* __restrict__ f2, __half* __restrict__ f3,
    float* __restrict__ el, float* __restrict__ er) {
  int b = blockIdx.x;
  int g, rb, n; const float* h; __half* fout;
  if (b < NB0)            { g = 0; rb = b;              n = P; h = acc1; fout = f0; }
  else if (b < 2 * NB0)   { g = 1; rb = b - NB0;        n = P; h = acc2; fout = f1; }
  else if (b < 2*NB0+NB2) { g = 2; rb = b - 2 * NB0;    n = M; h = acc1 + (size_t)P * F; fout = f2; }
  else                    { g = 3; rb = b - 2*NB0 - NB2; n = M; h = acc1 + (size_t)P * F; fout = f3; }
  int elo = (g == 0) ? 0 : (g == 1) ? P * H : (g == 2) ? 2 * P * H : (2 * P + M) * H;
  const float* W = gat_W + (size_t)g * F * F;
  __shared__ float hs[FR][F];
  int t = threadIdx.x;
  int r0 = rb * FR;
  for (int q = t; q < FR * 64; q += 256) {
    int r = q >> 6, ln = q & 63;
    int row = r0 + r;
    float4 v = {0.f, 0.f, 0.f, 0.f};
    if (row < n) v = *(const float4*)(h + (size_t)row * F + (ln << 2));
    *(float4*)&hs[r][ln << 2] = v;
  }
  __syncthreads();
  float acc[FR];
#pragma unroll
  for (int r = 0; r < FR; ++r) acc[r] = 0.f;
  for (int k = 0; k < F; k += 4) {
    float w0 = W[(size_t)k * F + t],       w1 = W[(size_t)(k + 1) * F + t],
          w2 = W[(size_t)(k + 2) * F + t], w3 = W[(size_t)(k + 3) * F + t];
#pragma unroll
    for (int r = 0; r < FR; ++r) {
      float4 h4 = *(const float4*)&hs[r][k];
      acc[r] += h4.x * w0 + h4.y * w1 + h4.z * w2 + h4.w * w3;
    }
  }
  int head = t >> 6, d = t & 63;           // one wave == one head
  float av = gat_al[g * H * DH + head * DH + d];
  float rv = gat_ar[g * H * DH + head * DH + d];
#pragma unroll
  for (int r = 0; r < FR; ++r) {
    int row = r0 + r;
    if (row < n) {
      fout[(size_t)row * F + t] = __float2half_rn(acc[r]);
      float cl = acc[r] * av, cr = acc[r] * rv;
      for (int o = 32; o > 0; o >>= 1) {
        cl += __shfl_down(cl, o, 64);
        cr += __shfl_down(cr, o, 64);
      }
      if (d == 0) { el[elo + row * H + head] = cl; er[elo + row * H + head] = cr; }
    }
  }
}

// ---------------------------------------------------------------------------
// All 4 GAT aggregations: TWO waves per dst-row (edge-parity split).
// Proven R0 form (sem fusion reverted: it was latency-bound, +50 us — R3).
// ---------------------------------------------------------------------------
__global__ __launch_bounds__(256) void k_gat_agg_all(
    const int* __restrict__ cu0, const unsigned* __restrict__ eg0,
    const int* __restrict__ cu1, const unsigned* __restrict__ eg1,
    const int* __restrict__ cu2, const unsigned* __restrict__ eg2,
    const int* __restrict__ cu3, const unsigned* __restrict__ eg3,
    const int* __restrict__ ovf_n, const int4* __restrict__ ovf,
    const float* __restrict__ el, const float* __restrict__ er,
    const __half* __restrict__ f0, const __half* __restrict__ f1,
    const __half* __restrict__ f2, const __half* __restrict__ f3,
    const float* __restrict__ gat_b,
    float* __restrict__ e0, float* __restrict__ e1,
    float* __restrict__ e2, float* __restrict__ e3) {
  int grp = (blockIdx.x * 256 + threadIdx.x) >> 7;
  int lane = threadIdx.x & 63;
  int wh   = (threadIdx.x >> 6) & 1;
  int gl   = threadIdx.x >> 7;
  int g, row; const int* cu; const unsigned* eg; const __half* feat; float* out; int elo;
  if (grp < P)            { g = 0; row = grp;             cu = cu0; eg = eg0; feat = f0; out = e0; elo = 0; }
  else if (grp < 2 * P)   { g = 1; row = grp - P;         cu = cu1; eg = eg1; feat = f1; out = e1; elo = P * H; }
  else if (grp < 2*P + M) { g = 2; row = grp - 2 * P;     cu = cu2; eg = eg2; feat = f2; out = e2; elo = 2 * P * H; }
  else                    { g = 3; row = grp - 2 * P - M; cu = cu3; eg = eg3; feat = f3; out = e3; elo = (2 * P + M) * H; }
  int head = lane >> 4;
  int fo = lane << 2;
  const float* elb = el + elo;
  float erv = er[elo + row * H + head];
  int deg = cu[(size_t)row * CPAD];
  int dn = deg < CAP_G ? deg : CAP_G;
  const unsigned* ps = eg + (size_t)row * CAP_G;
  int on = ovf_n[2 + g];
  const int4* ol = ovf + (2 + g) * OVF_CAP;
  // ---- pass 1: max over this wave's parity edges ----
  float mx = -3.4e38f;
  int i = wh;
  for (; i + 7 <= dn; i += 8) {     // 4 edges: i, i+2, i+4, i+6
    int s0 = (int)ps[i], s1 = (int)ps[i + 2], s2 = (int)ps[i + 4], s3 = (int)ps[i + 6];
    float a = elb[s0 * H + head] + erv, b = elb[s1 * H + head] + erv,
          c = elb[s2 * H + head] + erv, d = elb[s3 * H + head] + erv;
    a = a > 0.f ? a : 0.2f * a; b = b > 0.f ? b : 0.2f * b;
    c = c > 0.f ? c : 0.2f * c; d = d > 0.f ? d : 0.2f * d;
    mx = fmaxf(mx, fmaxf(fmaxf(a, b), fmaxf(c, d)));
  }
  for (; i < dn; i += 2) {
    float a = elb[(int)ps[i] * H + head] + erv;
    a = a > 0.f ? a : 0.2f * a;
    mx = fmaxf(mx, a);
  }
  if (wh == 0 && on > 0) {
    for (int k = 0; k < on; ++k) {
      int4 e = ol[k];
      if (e.x == row) {
        float a = elb[e.y * H + head] + erv;
        a = a > 0.f ? a : 0.2f * a;
        mx = fmaxf(mx, a);
      }
    }
  }
  __shared__ float mxs[2][2][64];
  mxs[gl][wh][lane] = mx;
  __syncthreads();
  mx = fmaxf(mxs[gl][0][lane], mxs[gl][1][lane]);
  // ---- pass 2: exp-sum + weighted aggregation over parity edges ----
  float ssum = 0.f;
  float4 acc = {0.f, 0.f, 0.f, 0.f};
  i = wh;
  for (; i + 3 <= dn; i += 4) {     // 2 edges: i, i+2
    int s0 = (int)ps[i], s1 = (int)ps[i + 2];
    float a = elb[s0 * H + head] + erv; a = a > 0.f ? a : 0.2f * a;
    float b = elb[s1 * H + head] + erv; b = b > 0.f ? b : 0.2f * b;
    float x0 = expf(a - mx), x1 = expf(b - mx);
    float4 q0 = h4_to_f4(feat + (size_t)s0 * F + fo);
    float4 q1 = h4_to_f4(feat + (size_t)s1 * F + fo);
    ssum += x0 + x1;
    acc.x += x0 * q0.x + x1 * q1.x;
    acc.y += x0 * q0.y + x1 * q1.y;
    acc.z += x0 * q0.z + x1 * q1.z;
    acc.w += x0 * q0.w + x1 * q1.w;
  }
  for (; i < dn; i += 2) {
    int s0 = (int)ps[i];
    float a = elb[s0 * H + head] + erv; a = a > 0.f ? a : 0.2f * a;
    float x0 = expf(a - mx);
    float4 q0 = h4_to_f4(feat + (size_t)s0 * F + fo);
    ssum += x0;
    acc.x += x0 * q0.x; acc.y += x0 * q0.y; acc.z += x0 * q0.z; acc.w += x0 * q0.w;
  }
  __shared__ float4 pacc[2][64];
  __shared__ float  pss[2][64];
  if (wh == 1) { pacc[gl][lane] = acc; pss[gl][lane] = ssum; }
  __syncthreads();
  if (wh == 1) return;
  {
    float4 pa = pacc[gl][lane];
    acc.x += pa.x; acc.y += pa.y; acc.z += pa.z; acc.w += pa.w;
    ssum += pss[gl][lane];
  }
  if (on > 0) {
    for (int k = 0; k < on; ++k) {
      int4 e = ol[k];
      if (e.x == row) {
        float a = elb[e.y * H + head] + erv; a = a > 0.f ? a : 0.2f * a;
        float x0 = expf(a - mx);
        float4 q0 = h4_to_f4(feat + (size_t)e.y * F + fo);
        ssum += x0;
        acc.x += x0 * q0.x; acc.y += x0 * q0.y; acc.z += x0 * q0.z; acc.w += x0 * q0.w;
      }
    }
  }
  float inv = 1.f / (ssum + 1e-9f);
  const float* bb = gat_b + g * F + fo;
  float4 v = {acc.x * inv + bb[0], acc.y * inv + bb[1],
              acc.z * inv + bb[2], acc.w * inv + bb[3]};
  v.x = v.x > 0.f ? v.x : expm1f(v.x);
  v.y = v.y > 0.f ? v.y : expm1f(v.y);
  v.z = v.z > 0.f ? v.z : expm1f(v.z);
  v.w = v.w > 0.f ? v.w : expm1f(v.w);
  *(float4*)(out + (size_t)row * F + fo) = v;
}

// ---------------------------------------------------------------------------
// Semantic attention weights. SR=4 (proven: W1 amortized over 4 rows, 4 ILP
// chains per load — this is why the R3 agg-fusion regressed).
// ---------------------------------------------------------------------------
constexpr int SR  = 4;
constexpr int SB0 = (P + SR - 1) / SR;   // 500
constexpr int SB2 = (M + SR - 1) / SR;   // 38
constexpr int SEM_BLOCKS = 2 * SB0 + 2 * SB2;

__global__ __launch_bounds__(128) void k_sem_w_all(
    const float* __restrict__ e0, const float* __restrict__ e1,
    const float* __restrict__ e2, const float* __restrict__ e3,
    const float* __restrict__ W1, const float* __restrict__ b1,
    const float* __restrict__ W2, float* __restrict__ w) {
  int b = blockIdx.x;
  int zid, rb, n; const float* z;
  if (b < SB0)            { zid = 0; rb = b;             n = P; z = e0; }
  else if (b < 2 * SB0)   { zid = 1; rb = b - SB0;       n = P; z = e1; }
  else if (b < 2*SB0+SB2) { zid = 2; rb = b - 2 * SB0;   n = M; z = e2; }
  else                    { zid = 3; rb = b - 2*SB0-SB2; n = M; z = e3; }
  __shared__ float zs[SR][F];
  int t = threadIdx.x;
  int r0 = rb * SR;
  for (int q = t; q < SR * 64; q += 128) {
    int r = q >> 6, ln = q & 63;
    int row = r0 + r;
    float4 v = {0.f, 0.f, 0.f, 0.f};
    if (row < n) v = *(const float4*)(z + (size_t)row * F + (ln << 2));
    *(float4*)&zs[r][ln << 2] = v;
  }
  __syncthreads();
  float hid[SR];
#pragma unroll
  for (int r = 0; r < SR; ++r) hid[r] = b1[t];
  for (int k = 0; k < F; k += 4) {
    float w0 = W1[(size_t)k * SA_HID + t],       w1 = W1[(size_t)(k + 1) * SA_HID + t],
          w2 = W1[(size_t)(k + 2) * SA_HID + t], w3 = W1[(size_t)(k + 3) * SA_HID + t];
#pragma unroll
    for (int r = 0; r < SR; ++r) {
      float4 z4 = *(const float4*)&zs[r][k];
      hid[r] += z4.x * w0 + z4.y * w1 + z4.z * w2 + z4.w * w3;
    }
  }
  float w2v = W2[t];
  float local = 0.f;
  for (int r = 0; r < SR; ++r) {
    int row = r0 + r;
    if (row < n) local += tanhf(hid[r]) * w2v;
  }
  for (int o = 32; o > 0; o >>= 1) local += __shfl_down(local, o, 64);
  __shared__ float pp[2];
  if ((t & 63) == 0) pp[t >> 6] = local;
  __syncthreads();
  if (t == 0) atomicAdd(&w[zid], pp[0] + pp[1]);
}

// ---------------------------------------------------------------------------
// Final (kept from R3): per block — recompute med combine + relu col-sum sv,
// c-vector, then patient beta-combine + simi GEMM for FIN_R rows.
// Block 0 additionally writes out_med. Removes k_med_cvec (serial block +
// one boundary) vs the 10-dispatch baseline.
// ---------------------------------------------------------------------------
constexpr int FIN_R = 8;   // P % FIN_R == 0 -> 250 blocks
__global__ __launch_bounds__(256) void k_final_all(
    const float* __restrict__ e0, const float* __restrict__ e1,
    const float* __restrict__ e2, const float* __restrict__ e3,
    const float* __restrict__ w, const float* __restrict__ outW,
    const float* __restrict__ outb,
    float* __restrict__ out_med, float* __restrict__ out_pat,
    float* __restrict__ simi) {
  int t = threadIdx.x;
  // betas
  float mm0 = w[2] * (1.f / M), mm1 = w[3] * (1.f / M);
  float mmx = fmaxf(mm0, mm1);
  float bm0 = expf(mm0 - mmx), bm1 = expf(mm1 - mmx);
  float msc = 1.f / (bm0 + bm1);
  bm0 *= msc; bm1 *= msc;
  float pm0 = w[0] * (1.f / P), pm1 = w[1] * (1.f / P);
  float pmx = fmaxf(pm0, pm1);
  float bp0 = expf(pm0 - pmx), bp1 = expf(pm1 - pmx);
  float psc = 1.f / (bp0 + bp1);
  bp0 *= psc; bp1 *= psc;
  // ---- med combine + relu col-sum (every block; block 0 writes out_med) ----
  constexpr int MED4 = M * F / 4;   // 9600
  float4 rs = {0.f, 0.f, 0.f, 0.f};
  bool wr_med = (blockIdx.x == 0);
  for (int j = t; j < MED4; j += 256) {
    float4 u0 = ((const float4*)e2)[j], u1 = ((const float4*)e3)[j];
    float4 r = {bm0 * u0.x + bm1 * u1.x, bm0 * u0.y + bm1 * u1.y,
                bm0 * u0.z + bm1 * u1.z, bm0 * u0.w + bm1 * u1.w};
    if (wr_med) ((float4*)out_med)[j] = r;
    rs.x += r.x > 0.f ? r.x : 0.f;
    rs.y += r.y > 0.f ? r.y : 0.f;
    rs.z += r.z > 0.f ? r.z : 0.f;
    rs.w += r.w > 0.f ? r.w : 0.f;
  }
  __shared__ float4 sv4[4][64];
  sv4[t >> 6][t & 63] = rs;
  __syncthreads();
  __shared__ float sv[F];
  if (t < 64) {
    float4 a = sv4[0][t], b = sv4[1][t], c = sv4[2][t], d = sv4[3][t];
    sv[t * 4 + 0] = a.x + b.x + c.x + d.x;
    sv[t * 4 + 1] = a.y + b.y + c.y + d.y;
    sv[t * 4 + 2] = a.z + b.z + c.z + d.z;
    sv[t * 4 + 3] = a.w + b.w + c.w + d.w;
  }
  __syncthreads();
  // ---- c-vector (per thread t < M), kept in register ----
  float cv = 0.f;
  if (t < M) {
    float cc = (float)M * outb[t];
    for (int f = 0; f < F; f += 4) {
      cc += sv[f]     * outW[(size_t)(F + f) * M + t]
          + sv[f + 1] * outW[(size_t)(F + f + 1) * M + t]
          + sv[f + 2] * outW[(size_t)(F + f + 2) * M + t]
          + sv[f + 3] * outW[(size_t)(F + f + 3) * M + t];
    }
    cv = cc;
  }
  // ---- patient combine + simi GEMM for FIN_R rows ----
  __shared__ float psh[FIN_R][F];
  int r0 = blockIdx.x * FIN_R;
  for (int q = t; q < FIN_R * 64; q += 256) {
    int r = q >> 6, ln = q & 63;
    size_t off = (size_t)(r0 + r) * F + (ln << 2);
    float4 u0 = *(const float4*)(e0 + off), u1 = *(const float4*)(e1 + off);
    float4 v = {bp0 * u0.x + bp1 * u1.x, bp0 * u0.y + bp1 * u1.y,
                bp0 * u0.z + bp1 * u1.z, bp0 * u0.w + bp1 * u1.w};
    *(float4*)(out_pat + off) = v;
    v.x = v.x > 0.f ? v.x : 0.f; v.y = v.y > 0.f ? v.y : 0.f;
    v.z = v.z > 0.f ? v.z : 0.f; v.w = v.w > 0.f ? v.w : 0.f;
    *(float4*)&psh[r][ln << 2] = v;
  }
  __syncthreads();
  if (t < M) {
    float acc[FIN_R];
#pragma unroll
    for (int r = 0; r < FIN_R; ++r) acc[r] = 0.f;
    for (int f = 0; f < F; f += 4) {
      float w0 = outW[(size_t)f * M + t],       w1 = outW[(size_t)(f + 1) * M + t],
            w2 = outW[(size_t)(f + 2) * M + t], w3 = outW[(size_t)(f + 3) * M + t];
#pragma unroll
      for (int r = 0; r < FIN_R; ++r) {
        float4 p4 = *(const float4*)&psh[r][f];
        acc[r] += p4.x * w0 + p4.y * w1 + p4.z * w2 + p4.w * w3;
      }
    }
#pragma unroll
    for (int r = 0; r < FIN_R; ++r)
      simi[(size_t)(r0 + r) * M + t] = (float)M * acc[r] + cv;
  }
}

// ---------------------------------------------------------------------------
extern "C" void kernel_launch(void* const* d_in, const int* in_sizes, int n_in,
                              void* d_out, int out_size, void* d_ws, size_t ws_size,
                              hipStream_t stream) {
  const int*   adj1_rows = (const int*)d_in[0];
  const int*   adj1_cols = (const int*)d_in[1];
  const float* adj1_vals = (const float*)d_in[2];
  const int*   adj2_rows = (const int*)d_in[3];
  const int*   adj2_cols = (const int*)d_in[4];
  const float* adj2_vals = (const float*)d_in[5];
  const int*   g0_src = (const int*)d_in[6];
  const int*   g0_dst = (const int*)d_in[7];
  const int*   g1_src = (const int*)d_in[8];
  const int*   g1_dst = (const int*)d_in[9];
  const int*   g2_src = (const int*)d_in[10];
  const int*   g2_dst = (const int*)d_in[11];
  const int*   g3_src = (const int*)d_in[12];
  const int*   g3_dst = (const int*)d_in[13];
  // d_in[14] = keepRate (unused, == 1)
  const float* pE     = (const float*)d_in[15];
  const float* mE     = (const float*)d_in[16];
  const float* dE     = (const float*)d_in[17];
  const float* gat_W  = (const float*)d_in[18];
  const float* gat_al = (const float*)d_in[19];
  const float* gat_ar = (const float*)d_in[20];
  const float* gat_b  = (const float*)d_in[21];
  const float* sa_W1  = (const float*)d_in[22];
  const float* sa_b1  = (const float*)d_in[23];
  const float* sa_W2  = (const float*)d_in[24];
  const float* out_W  = (const float*)d_in[25];
  const float* out_b  = (const float*)d_in[26];

  // ---- workspace layout: [zeroed (padded counters) | ELL | fp16 | fp32] ----
  int* ip = (int*)d_ws;
  int* cur1 = ip; ip += (size_t)N1 * CPAD;
  int* cur2 = ip; ip += (size_t)N2 * CPAD;
  int* cu0  = ip; ip += (size_t)P * CPAD;
  int* cu1  = ip; ip += (size_t)P * CPAD;
  int* cu2  = ip; ip += (size_t)M * CPAD;
  int* cu3  = ip; ip += (size_t)M * CPAD;
  int* ovf_n = ip; ip += 6;
  float* wbuf = (float*)ip; ip += 4;
  size_t memset_bytes = (size_t)((char*)ip - (char*)d_ws);

  uintptr_t up = ((uintptr_t)ip + 15) & ~(uintptr_t)15;
  int4* ovf = (int4*)up;                       // 6 * OVF_CAP
  uint2* ell1 = (uint2*)(ovf + 6 * OVF_CAP);   // N1 * CAP_A
  uint2* ell2 = ell1 + (size_t)N1 * CAP_A;     // N2 * CAP_A
  unsigned* eg0 = (unsigned*)(ell2 + (size_t)N2 * CAP_A);
  unsigned* eg1 = eg0 + (size_t)P * CAP_G;
  unsigned* eg2 = eg1 + (size_t)P * CAP_G;
  unsigned* eg3 = eg2 + (size_t)M * CAP_G;
  // fp16 region (16B-aligned by construction)
  __half* hp = (__half*)(eg3 + (size_t)M * CAP_G);
  __half* pEh   = hp; hp += (size_t)P * F;
  __half* mEh   = hp; hp += (size_t)M * F;
  __half* dEh   = hp; hp += (size_t)DG * F;
  __half* lat1h = hp; hp += (size_t)N1 * F;
  __half* lat2h = hp; hp += (size_t)N2 * F;
  __half* f0h   = hp; hp += (size_t)P * F;
  __half* f1h   = hp; hp += (size_t)P * F;
  __half* f2h   = hp; hp += (size_t)M * F;
  __half* f3h   = hp; hp += (size_t)M * F;
  float* fp = (float*)hp;
  float* lat1f = fp; fp += (size_t)N1 * F;
  float* lat2f = fp; fp += (size_t)N2 * F;
  float* acc1  = fp; fp += (size_t)N1 * F;
  float* acc2  = fp; fp += (size_t)N2 * F;
  float* el    = fp; fp += (size_t)(2 * P + 2 * M) * H;
  float* er    = fp; fp += (size_t)(2 * P + 2 * M) * H;
  float* e0b   = fp; fp += (size_t)P * F;
  float* e1b   = fp; fp += (size_t)P * F;
  float* e2b   = fp; fp += (size_t)M * F;
  float* e3b   = fp; fp += (size_t)M * F;

  // ---- output layout: (simi_pm, d_gcn, med, m_gcn, patient) ----
  float* out_simi = (float*)d_out;               // P*M
  float* out_dgcn = out_simi + (size_t)P * M;    // DG*F
  float* out_med  = out_dgcn + (size_t)DG * F;   // M*F
  float* out_mgcn = out_med  + (size_t)M * F;    // M*F
  float* out_pat  = out_mgcn + (size_t)M * F;    // P*F

  // ---- zero padded counters (~540 KB) ----
  hipMemsetAsync(d_ws, 0, memset_bytes, stream);

  // ---- ELL build + fused fp16 embed cast: ONE dispatch ----
  int eb = ((HOE + 3) / 4 + 255) / 256;
  k_build<<<eb, 256, 0, stream>>>(adj1_rows, adj1_cols, adj1_vals,
                                  adj2_rows, adj2_cols, adj2_vals,
                                  g0_dst, g0_src, g1_dst, g1_src,
                                  g2_dst, g2_src, g3_dst, g3_src,
                                  cur1, ell1, cur2, ell2,
                                  cu0, eg0, cu1, eg1, cu2, eg2, cu3, eg3,
                                  ovf_n, ovf,
                                  pE, mE, dE, pEh, mEh, dEh);

  // ---- GNN: 2 layers, 2 waves per row (edge-parity split) ----
  int sb = (N1 + N2) / 2;
  k_spmm<1><<<sb, 256, 0, stream>>>(cur1, ell1, cur2, ell2, ovf_n, ovf,
                                    pEh, mEh, dEh, lat1f, lat2f, lat1h, lat2h,
                                    acc1, acc2, out_mgcn, out_dgcn);
  k_spmm<2><<<sb, 256, 0, stream>>>(cur1, ell1, cur2, ell2, ovf_n, ovf,
                                    pEh, mEh, dEh, lat1f, lat2f, lat1h, lat2h,
                                    acc1, acc2, out_mgcn, out_dgcn);

  // ---- 4 GATs: scalar feature GEMM + 2-wave-split aggregation ----
  k_gat_feat_all<<<FEAT_BLOCKS, 256, 0, stream>>>(acc1, acc2, gat_W, gat_al, gat_ar,
                                                  f0h, f1h, f2h, f3h, el, er);
  int ab = (2 * P + 2 * M) / 2;   // 4300 groups * 128 threads / 256
  k_gat_agg_all<<<ab, 256, 0, stream>>>(cu0, eg0, cu1, eg1, cu2, eg2, cu3, eg3,
                                        ovf_n, ovf, el, er, f0h, f1h, f2h, f3h, gat_b,
                                        e0b, e1b, e2b, e3b);

  // ---- semantic attention weights ----
  k_sem_w_all<<<SEM_BLOCKS, 128, 0, stream>>>(e0b, e1b, e2b, e3b, sa_W1, sa_b1, sa_W2, wbuf);

  // ---- final: med+cvec recompute-per-block + patient combine + simi ----
  k_final_all<<<P / FIN_R, 256, 0, stream>>>(e0b, e1b, e2b, e3b, wbuf, out_W, out_b,
                                             out_med, out_pat, out_simi);
}

// Round 5
// 304.639 us; speedup vs baseline: 3.3231x; 1.0155x over previous
//
#include <hip/hip_runtime.h>
#include <hip/hip_fp16.h>
#include <cmath>
#include <cstdint>

// Problem constants (fixed by the reference).
constexpr int P  = 2000, M = 150, DG = 2000, F = 256, H = 4, DH = 64;
constexpr int N1 = P + M;          // 2150
constexpr int N2 = P + DG;         // 4000
constexpr int E1 = 137600, E2 = 256000, EGP = 64000, EGM = 4800;
constexpr int SA_HID = 128;

// Edge-range offsets for the fused build kernel.
constexpr int HO1 = E1, HO2 = E1 + E2, HO3 = HO2 + EGP, HO4 = HO3 + EGP,
              HO5 = HO4 + EGM, HOE = HO5 + EGM;   // 531200 total edges

// ELL capacities (overflow list guarantees correctness regardless).
constexpr int CAP_A = 160;
constexpr int CAP_G = 96;
constexpr int OVF_CAP = 4096;

// One counter per 64B line (R7: removed same-line atomic serialization).
constexpr int CPAD = 16;

// ---- fp16 helpers -----------------------------------------------------------
__device__ __forceinline__ float4 h4_to_f4(const __half* p) {
  union { ushort4 u4; __half2 h2[2]; } u;
  u.u4 = *(const ushort4*)p;
  float2 lo = __half22float2(u.h2[0]);
  float2 hi = __half22float2(u.h2[1]);
  return make_float4(lo.x, lo.y, hi.x, hi.y);
}
__device__ __forceinline__ void f4_to_h4(__half* p, float4 v) {
  union { ushort4 u4; __half2 h2[2]; } u;
  u.h2[0] = __float22half2_rn(make_float2(v.x, v.y));
  u.h2[1] = __float22half2_rn(make_float2(v.z, v.w));
  *(ushort4*)p = u.u4;
}

// ---------------------------------------------------------------------------
// ELL build (padded counters) + fused fp32->fp16 embed cast.
// ---------------------------------------------------------------------------
constexpr int CAST_CH = (P * F + M * F + DG * F) / 8;   // 8-float chunks

__global__ __launch_bounds__(256) void k_build(
    const int* __restrict__ a1r, const int* __restrict__ a1c, const float* __restrict__ a1v,
    const int* __restrict__ a2r, const int* __restrict__ a2c, const float* __restrict__ a2v,
    const int* __restrict__ d0, const int* __restrict__ s0,
    const int* __restrict__ d1, const int* __restrict__ s1,
    const int* __restrict__ d2, const int* __restrict__ s2,
    const int* __restrict__ d3, const int* __restrict__ s3,
    int* cur1, uint2* ell1, int* cur2, uint2* ell2,
    int* cu0, unsigned* eg0, int* cu1, unsigned* eg1,
    int* cu2, unsigned* eg2, int* cu3, unsigned* eg3,
    int* __restrict__ ovf_n, int4* __restrict__ ovf,
    const float* __restrict__ pEf, const float* __restrict__ mEf,
    const float* __restrict__ dEf,
    __half* __restrict__ pEh, __half* __restrict__ mEh, __half* __restrict__ dEh) {
  int tid = blockIdx.x * 256 + threadIdx.x;
  int T = gridDim.x * 256;
  int seg[4], row[4]; unsigned p0[4], p1[4];
#pragma unroll
  for (int u = 0; u < 4; ++u) {
    int i = tid + u * T;
    seg[u] = -1;
    if (i < HOE) {
      if (i < HO1)      { seg[u] = 0; row[u] = a1r[i]; p0[u] = (unsigned)a1c[i]; p1[u] = __float_as_uint(a1v[i]); }
      else if (i < HO2) { int j = i - HO1; seg[u] = 1; row[u] = a2r[j]; p0[u] = (unsigned)a2c[j]; p1[u] = __float_as_uint(a2v[j]); }
      else if (i < HO3) { int j = i - HO2; seg[u] = 2; row[u] = d0[j]; p0[u] = (unsigned)s0[j]; }
      else if (i < HO4) { int j = i - HO3; seg[u] = 3; row[u] = d1[j]; p0[u] = (unsigned)s1[j]; }
      else if (i < HO5) { int j = i - HO4; seg[u] = 4; row[u] = d2[j]; p0[u] = (unsigned)s2[j]; }
      else              { int j = i - HO5; seg[u] = 5; row[u] = d3[j]; p0[u] = (unsigned)s3[j]; }
    }
  }
#pragma unroll
  for (int u = 0; u < 4; ++u) {
    int r = row[u];
    switch (seg[u]) {
      case 0: { int slot = atomicAdd(&cur1[(size_t)r * CPAD], 1);
        if (slot < CAP_A) ell1[(size_t)r * CAP_A + slot] = make_uint2(p0[u], p1[u]);
        else { int o = atomicAdd(&ovf_n[0], 1); if (o < OVF_CAP) ovf[0 * OVF_CAP + o] = make_int4(r, (int)p0[u], (int)p1[u], 0); } } break;
      case 1: { int slot = atomicAdd(&cur2[(size_t)r * CPAD], 1);
        if (slot < CAP_A) ell2[(size_t)r * CAP_A + slot] = make_uint2(p0[u], p1[u]);
        else { int o = atomicAdd(&ovf_n[1], 1); if (o < OVF_CAP) ovf[1 * OVF_CAP + o] = make_int4(r, (int)p0[u], (int)p1[u], 0); } } break;
      case 2: { int slot = atomicAdd(&cu0[(size_t)r * CPAD], 1);
        if (slot < CAP_G) eg0[(size_t)r * CAP_G + slot] = p0[u];
        else { int o = atomicAdd(&ovf_n[2], 1); if (o < OVF_CAP) ovf[2 * OVF_CAP + o] = make_int4(r, (int)p0[u], 0, 0); } } break;
      case 3: { int slot = atomicAdd(&cu1[(size_t)r * CPAD], 1);
        if (slot < CAP_G) eg1[(size_t)r * CAP_G + slot] = p0[u];
        else { int o = atomicAdd(&ovf_n[3], 1); if (o < OVF_CAP) ovf[3 * OVF_CAP + o] = make_int4(r, (int)p0[u], 0, 0); } } break;
      case 4: { int slot = atomicAdd(&cu2[(size_t)r * CPAD], 1);
        if (slot < CAP_G) eg2[(size_t)r * CAP_G + slot] = p0[u];
        else { int o = atomicAdd(&ovf_n[4], 1); if (o < OVF_CAP) ovf[4 * OVF_CAP + o] = make_int4(r, (int)p0[u], 0, 0); } } break;
      case 5: { int slot = atomicAdd(&cu3[(size_t)r * CPAD], 1);
        if (slot < CAP_G) eg3[(size_t)r * CAP_G + slot] = p0[u];
        else { int o = atomicAdd(&ovf_n[5], 1); if (o < OVF_CAP) ovf[5 * OVF_CAP + o] = make_int4(r, (int)p0[u], 0, 0); } } break;
      default: break;
    }
  }
  // Fused embed cast fp32 -> fp16 (independent streaming work).
  for (int c = tid; c < CAST_CH; c += T) {
    int j = c * 8;
    const float* src; __half* dst;
    if (j < P * F)              { src = pEf + j;               dst = pEh + j; }
    else if (j < P * F + M * F) { src = mEf + (j - P * F);     dst = mEh + (j - P * F); }
    else                        { src = dEf + (j - P*F - M*F); dst = dEh + (j - P*F - M*F); }
    float4 a = *(const float4*)src, b = *(const float4*)(src + 4);
    f4_to_h4(dst, a);
    f4_to_h4(dst + 4, b);
  }
}

// ---------------------------------------------------------------------------
// SPMM: TWO waves per row (edges split by parity, LDS combine), fp16 gathers,
// fp32 accumulate (R9 structure, proven).
// ---------------------------------------------------------------------------
template<int LAYER>
__global__ __launch_bounds__(256) void k_spmm(
    const int* __restrict__ cur1, const uint2* __restrict__ ell1,
    const int* __restrict__ cur2, const uint2* __restrict__ ell2,
    const int* __restrict__ ovf_n, const int4* __restrict__ ovf,
    const __half* __restrict__ pEh, const __half* __restrict__ mEh,
    const __half* __restrict__ dEh,
    float* __restrict__ lat1f, float* __restrict__ lat2f,
    __half* __restrict__ lat1h, __half* __restrict__ lat2h,
    float* __restrict__ acc1, float* __restrict__ acc2,
    float* __restrict__ out_mgcn, float* __restrict__ out_dgcn) {
  int grp = (blockIdx.x * 256 + threadIdx.x) >> 7;   // row-group id
  int lane = threadIdx.x & 63;
  int wh   = (threadIdx.x >> 6) & 1;                 // wave-half within group
  int gl   = threadIdx.x >> 7;                       // group slot in block (0/1)
  bool g2 = grp >= N1;
  int row = g2 ? grp - N1 : grp;
  const uint2* pe = (g2 ? ell2 : ell1) + (size_t)row * CAP_A;
  const __half* latinh = g2 ? lat2h : lat1h;
  const __half* tailEh = g2 ? dEh : mEh;
  int deg = (g2 ? cur2 : cur1)[(size_t)row * CPAD];
  int dn = deg < CAP_A ? deg : CAP_A;
  int fo = lane << 2;
  float4 s = {0.f, 0.f, 0.f, 0.f};
  auto fetch = [&](int c) -> float4 {
    const __half* b;
    if (LAYER == 1) b = (c < P) ? (pEh + (size_t)c * F) : (tailEh + (size_t)(c - P) * F);
    else            b = latinh + (size_t)c * F;
    return h4_to_f4(b + fo);
  };
  int i = wh;
  for (; i + 15 <= dn; i += 16) {    // 8 edges: i, i+2, ..., i+14
    uint2 m[8]; float4 a[8];
#pragma unroll
    for (int u = 0; u < 8; ++u) m[u] = pe[i + 2 * u];
#pragma unroll
    for (int u = 0; u < 8; ++u) a[u] = fetch((int)m[u].x);
#pragma unroll
    for (int u = 0; u < 8; ++u) {
      float v = __uint_as_float(m[u].y);
      s.x += v * a[u].x; s.y += v * a[u].y; s.z += v * a[u].z; s.w += v * a[u].w;
    }
  }
  for (; i < dn; i += 2) {
    uint2 m = pe[i];
    float v = __uint_as_float(m.y);
    float4 a = fetch((int)m.x);
    s.x += v * a.x; s.y += v * a.y; s.z += v * a.z; s.w += v * a.w;
  }
  __shared__ float part[2][F];
  if (wh == 1) *(float4*)&part[gl][fo] = s;
  __syncthreads();
  if (wh == 1) return;
  {
    float4 p = *(const float4*)&part[gl][fo];
    s.x += p.x; s.y += p.y; s.z += p.z; s.w += p.w;
  }
  // Overflow edges (normally zero), wave 0 only.
  {
    int gi = g2 ? 1 : 0;
    int on = ovf_n[gi];
    if (on > 0) {
      const int4* ol = ovf + gi * OVF_CAP;
      for (int k = 0; k < on; ++k) {
        int4 e = ol[k];
        if (e.x == row) {
          float v = __int_as_float(e.z);
          float4 a = fetch(e.y);
          s.x += v * a.x; s.y += v * a.y; s.z += v * a.z; s.w += v * a.w;
        }
      }
    }
  }
  float4 l;
  l.x = s.x > 0.f ? s.x : 0.5f * s.x;
  l.y = s.y > 0.f ? s.y : 0.5f * s.y;
  l.z = s.z > 0.f ? s.z : 0.5f * s.z;
  l.w = s.w > 0.f ? s.w : 0.5f * s.w;
  if (LAYER == 1) {
    *(float4*)((g2 ? lat2f : lat1f) + (size_t)row * F + fo) = l;   // exact own-row
    f4_to_h4((g2 ? lat2h : lat1h) + (size_t)row * F + fo, l);      // gather copy
  } else {
    const float* latf = g2 ? lat2f : lat1f;
    float4 b = *(const float4*)(latf + (size_t)row * F + fo);
    float4 a = {b.x + l.x, b.y + l.y, b.z + l.z, b.w + l.w};
    *(float4*)((g2 ? acc2 : acc1) + (size_t)row * F + fo) = a;
    if (row >= P)
      *(float4*)((g2 ? out_dgcn : out_mgcn) + (size_t)(row - P) * F + fo) = a;
  }
}

// ---------------------------------------------------------------------------
// All 4 GAT feature GEMMs. FR=8 (R8/R9: occupancy beats W-traffic reduction).
// ---------------------------------------------------------------------------
constexpr int FR  = 8;
constexpr int NB0 = (P + FR - 1) / FR;   // 250
constexpr int NB2 = (M + FR - 1) / FR;   // 19
constexpr int FEAT_BLOCKS = 2 * NB0 + 2 * NB2;

__global__ __launch_bounds__(256) void k_gat_feat_all(
    const float* __restrict__ acc1, const float* __restrict__ acc2,
    const float* __restrict__ gat_W, const float* __restrict__ gat_al,
    const float* __restrict__ gat_ar,
    __half* __restrict__ f0, __half* __restrict__ f1,
    __half* __restrict__ f2, __half* __restrict__ f3,
    float* __restrict__ el, float* __restrict__ er) {
  int b = blockIdx.x;
  int g, rb, n; const float* h; __half* fout;
  if (b < NB0)            { g = 0; rb = b;              n = P; h = acc1; fout = f0; }
  else if (b < 2 * NB0)   { g = 1; rb = b - NB0;        n = P; h = acc2; fout = f1; }
  else if (b < 2*NB0+NB2) { g = 2; rb = b - 2 * NB0;    n = M; h = acc1 + (size_t)P * F; fout = f2; }
  else                    { g = 3; rb = b - 2*NB0 - NB2; n = M; h = acc1 + (size_t)P * F; fout = f3; }
  int elo = (g == 0) ? 0 : (g == 1) ? P * H : (g == 2) ? 2 * P * H : (2 * P + M) * H;
  const float* W = gat_W + (size_t)g * F * F;
  __shared__ float hs[FR][F];
  int t = threadIdx.x;
  int r0 = rb * FR;
  for (int q = t; q < FR * 64; q += 256) {
    int r = q >> 6, ln = q & 63;
    int row = r0 + r;
    float4 v = {0.f, 0.f, 0.f, 0.f};
    if (row < n) v = *(const float4*)(h + (size_t)row * F + (ln << 2));
    *(float4*)&hs[r][ln << 2] = v;
  }
  __syncthreads();
  float acc[FR];
#pragma unroll
  for (int r = 0; r < FR; ++r) acc[r] = 0.f;
  for (int k = 0; k < F; k += 4) {
    float w0 = W[(size_t)k * F + t],       w1 = W[(size_t)(k + 1) * F + t],
          w2 = W[(size_t)(k + 2) * F + t], w3 = W[(size_t)(k + 3) * F + t];
#pragma unroll
    for (int r = 0; r < FR; ++r) {
      float4 h4 = *(const float4*)&hs[r][k];
      acc[r] += h4.x * w0 + h4.y * w1 + h4.z * w2 + h4.w * w3;
    }
  }
  int head = t >> 6, d = t & 63;           // one wave == one head
  float av = gat_al[g * H * DH + head * DH + d];
  float rv = gat_ar[g * H * DH + head * DH + d];
#pragma unroll
  for (int r = 0; r < FR; ++r) {
    int row = r0 + r;
    if (row < n) {
      fout[(size_t)row * F + t] = __float2half_rn(acc[r]);
      float cl = acc[r] * av, cr = acc[r] * rv;
      for (int o = 32; o > 0; o >>= 1) {
        cl += __shfl_down(cl, o, 64);
        cr += __shfl_down(cr, o, 64);
      }
      if (d == 0) { el[elo + row * H + head] = cl; er[elo + row * H + head] = cr; }
    }
  }
}

// ---------------------------------------------------------------------------
// All 4 GAT aggregations: TWO waves per dst-row (edge-parity split).
// R5: pass-2 unrolled to 4 edge gathers in flight.
// ---------------------------------------------------------------------------
__global__ __launch_bounds__(256) void k_gat_agg_all(
    const int* __restrict__ cu0, const unsigned* __restrict__ eg0,
    const int* __restrict__ cu1, const unsigned* __restrict__ eg1,
    const int* __restrict__ cu2, const unsigned* __restrict__ eg2,
    const int* __restrict__ cu3, const unsigned* __restrict__ eg3,
    const int* __restrict__ ovf_n, const int4* __restrict__ ovf,
    const float* __restrict__ el, const float* __restrict__ er,
    const __half* __restrict__ f0, const __half* __restrict__ f1,
    const __half* __restrict__ f2, const __half* __restrict__ f3,
    const float* __restrict__ gat_b,
    float* __restrict__ e0, float* __restrict__ e1,
    float* __restrict__ e2, float* __restrict__ e3) {
  int grp = (blockIdx.x * 256 + threadIdx.x) >> 7;
  int lane = threadIdx.x & 63;
  int wh   = (threadIdx.x >> 6) & 1;
  int gl   = threadIdx.x >> 7;
  int g, row; const int* cu; const unsigned* eg; const __half* feat; float* out; int elo;
  if (grp < P)            { g = 0; row = grp;             cu = cu0; eg = eg0; feat = f0; out = e0; elo = 0; }
  else if (grp < 2 * P)   { g = 1; row = grp - P;         cu = cu1; eg = eg1; feat = f1; out = e1; elo = P * H; }
  else if (grp < 2*P + M) { g = 2; row = grp - 2 * P;     cu = cu2; eg = eg2; feat = f2; out = e2; elo = 2 * P * H; }
  else                    { g = 3; row = grp - 2 * P - M; cu = cu3; eg = eg3; feat = f3; out = e3; elo = (2 * P + M) * H; }
  int head = lane >> 4;
  int fo = lane << 2;
  const float* elb = el + elo;
  float erv = er[elo + row * H + head];
  int deg = cu[(size_t)row * CPAD];
  int dn = deg < CAP_G ? deg : CAP_G;
  const unsigned* ps = eg + (size_t)row * CAP_G;
  int on = ovf_n[2 + g];
  const int4* ol = ovf + (2 + g) * OVF_CAP;
  // ---- pass 1: max over this wave's parity edges ----
  float mx = -3.4e38f;
  int i = wh;
  for (; i + 7 <= dn; i += 8) {     // 4 edges: i, i+2, i+4, i+6
    int s0 = (int)ps[i], s1 = (int)ps[i + 2], s2 = (int)ps[i + 4], s3 = (int)ps[i + 6];
    float a = elb[s0 * H + head] + erv, b = elb[s1 * H + head] + erv,
          c = elb[s2 * H + head] + erv, d = elb[s3 * H + head] + erv;
    a = a > 0.f ? a : 0.2f * a; b = b > 0.f ? b : 0.2f * b;
    c = c > 0.f ? c : 0.2f * c; d = d > 0.f ? d : 0.2f * d;
    mx = fmaxf(mx, fmaxf(fmaxf(a, b), fmaxf(c, d)));
  }
  for (; i < dn; i += 2) {
    float a = elb[(int)ps[i] * H + head] + erv;
    a = a > 0.f ? a : 0.2f * a;
    mx = fmaxf(mx, a);
  }
  if (wh == 0 && on > 0) {
    for (int k = 0; k < on; ++k) {
      int4 e = ol[k];
      if (e.x == row) {
        float a = elb[e.y * H + head] + erv;
        a = a > 0.f ? a : 0.2f * a;
        mx = fmaxf(mx, a);
      }
    }
  }
  __shared__ float mxs[2][2][64];
  mxs[gl][wh][lane] = mx;
  __syncthreads();
  mx = fmaxf(mxs[gl][0][lane], mxs[gl][1][lane]);
  // ---- pass 2: exp-sum + weighted aggregation, 4 gathers in flight ----
  float ssum = 0.f;
  float4 acc = {0.f, 0.f, 0.f, 0.f};
  i = wh;
  for (; i + 7 <= dn; i += 8) {     // 4 edges: i, i+2, i+4, i+6
    int s0 = (int)ps[i], s1 = (int)ps[i + 2], s2 = (int)ps[i + 4], s3 = (int)ps[i + 6];
    float a = elb[s0 * H + head] + erv; a = a > 0.f ? a : 0.2f * a;
    float b = elb[s1 * H + head] + erv; b = b > 0.f ? b : 0.2f * b;
    float c = elb[s2 * H + head] + erv; c = c > 0.f ? c : 0.2f * c;
    float d = elb[s3 * H + head] + erv; d = d > 0.f ? d : 0.2f * d;
    float x0 = expf(a - mx), x1 = expf(b - mx), x2 = expf(c - mx), x3 = expf(d - mx);
    float4 q0 = h4_to_f4(feat + (size_t)s0 * F + fo);
    float4 q1 = h4_to_f4(feat + (size_t)s1 * F + fo);
    float4 q2 = h4_to_f4(feat + (size_t)s2 * F + fo);
    float4 q3 = h4_to_f4(feat + (size_t)s3 * F + fo);
    ssum += (x0 + x1) + (x2 + x3);
    acc.x += x0 * q0.x + x1 * q1.x + x2 * q2.x + x3 * q3.x;
    acc.y += x0 * q0.y + x1 * q1.y + x2 * q2.y + x3 * q3.y;
    acc.z += x0 * q0.z + x1 * q1.z + x2 * q2.z + x3 * q3.z;
    acc.w += x0 * q0.w + x1 * q1.w + x2 * q2.w + x3 * q3.w;
  }
  for (; i + 3 <= dn; i += 4) {     // 2 edges
    int s0 = (int)ps[i], s1 = (int)ps[i + 2];
    float a = elb[s0 * H + head] + erv; a = a > 0.f ? a : 0.2f * a;
    float b = elb[s1 * H + head] + erv; b = b > 0.f ? b : 0.2f * b;
    float x0 = expf(a - mx), x1 = expf(b - mx);
    float4 q0 = h4_to_f4(feat + (size_t)s0 * F + fo);
    float4 q1 = h4_to_f4(feat + (size_t)s1 * F + fo);
    ssum += x0 + x1;
    acc.x += x0 * q0.x + x1 * q1.x;
    acc.y += x0 * q0.y + x1 * q1.y;
    acc.z += x0 * q0.z + x1 * q1.z;
    acc.w += x0 * q0.w + x1 * q1.w;
  }
  for (; i < dn; i += 2) {
    int s0 = (int)ps[i];
    float a = elb[s0 * H + head] + erv; a = a > 0.f ? a : 0.2f * a;
    float x0 = expf(a - mx);
    float4 q0 = h4_to_f4(feat + (size_t)s0 * F + fo);
    ssum += x0;
    acc.x += x0 * q0.x; acc.y += x0 * q0.y; acc.z += x0 * q0.z; acc.w += x0 * q0.w;
  }
  __shared__ float4 pacc[2][64];
  __shared__ float  pss[2][64];
  if (wh == 1) { pacc[gl][lane] = acc; pss[gl][lane] = ssum; }
  __syncthreads();
  if (wh == 1) return;
  {
    float4 pa = pacc[gl][lane];
    acc.x += pa.x; acc.y += pa.y; acc.z += pa.z; acc.w += pa.w;
    ssum += pss[gl][lane];
  }
  if (on > 0) {
    for (int k = 0; k < on; ++k) {
      int4 e = ol[k];
      if (e.x == row) {
        float a = elb[e.y * H + head] + erv; a = a > 0.f ? a : 0.2f * a;
        float x0 = expf(a - mx);
        float4 q0 = h4_to_f4(feat + (size_t)e.y * F + fo);
        ssum += x0;
        acc.x += x0 * q0.x; acc.y += x0 * q0.y; acc.z += x0 * q0.z; acc.w += x0 * q0.w;
      }
    }
  }
  float inv = 1.f / (ssum + 1e-9f);
  const float* bb = gat_b + g * F + fo;
  float4 v = {acc.x * inv + bb[0], acc.y * inv + bb[1],
              acc.z * inv + bb[2], acc.w * inv + bb[3]};
  v.x = v.x > 0.f ? v.x : expm1f(v.x);
  v.y = v.y > 0.f ? v.y : expm1f(v.y);
  v.z = v.z > 0.f ? v.z : expm1f(v.z);
  v.w = v.w > 0.f ? v.w : expm1f(v.w);
  *(float4*)(out + (size_t)row * F + fo) = v;
}

// ---------------------------------------------------------------------------
// Semantic attention weights. SR=4 (proven: W1 amortized over 4 rows, 4 ILP
// chains per load).
// ---------------------------------------------------------------------------
constexpr int SR  = 4;
constexpr int SB0 = (P + SR - 1) / SR;   // 500
constexpr int SB2 = (M + SR - 1) / SR;   // 38
constexpr int SEM_BLOCKS = 2 * SB0 + 2 * SB2;

__global__ __launch_bounds__(128) void k_sem_w_all(
    const float* __restrict__ e0, const float* __restrict__ e1,
    const float* __restrict__ e2, const float* __restrict__ e3,
    const float* __restrict__ W1, const float* __restrict__ b1,
    const float* __restrict__ W2, float* __restrict__ w) {
  int b = blockIdx.x;
  int zid, rb, n; const float* z;
  if (b < SB0)            { zid = 0; rb = b;             n = P; z = e0; }
  else if (b < 2 * SB0)   { zid = 1; rb = b - SB0;       n = P; z = e1; }
  else if (b < 2*SB0+SB2) { zid = 2; rb = b - 2 * SB0;   n = M; z = e2; }
  else                    { zid = 3; rb = b - 2*SB0-SB2; n = M; z = e3; }
  __shared__ float zs[SR][F];
  int t = threadIdx.x;
  int r0 = rb * SR;
  for (int q = t; q < SR * 64; q += 128) {
    int r = q >> 6, ln = q & 63;
    int row = r0 + r;
    float4 v = {0.f, 0.f, 0.f, 0.f};
    if (row < n) v = *(const float4*)(z + (size_t)row * F + (ln << 2));
    *(float4*)&zs[r][ln << 2] = v;
  }
  __syncthreads();
  float hid[SR];
#pragma unroll
  for (int r = 0; r < SR; ++r) hid[r] = b1[t];
  for (int k = 0; k < F; k += 4) {
    float w0 = W1[(size_t)k * SA_HID + t],       w1 = W1[(size_t)(k + 1) * SA_HID + t],
          w2 = W1[(size_t)(k + 2) * SA_HID + t], w3 = W1[(size_t)(k + 3) * SA_HID + t];
#pragma unroll
    for (int r = 0; r < SR; ++r) {
      float4 z4 = *(const float4*)&zs[r][k];
      hid[r] += z4.x * w0 + z4.y * w1 + z4.z * w2 + z4.w * w3;
    }
  }
  float w2v = W2[t];
  float local = 0.f;
  for (int r = 0; r < SR; ++r) {
    int row = r0 + r;
    if (row < n) local += tanhf(hid[r]) * w2v;
  }
  for (int o = 32; o > 0; o >>= 1) local += __shfl_down(local, o, 64);
  __shared__ float pp[2];
  if ((t & 63) == 0) pp[t >> 6] = local;
  __syncthreads();
  if (t == 0) atomicAdd(&w[zid], pp[0] + pp[1]);
}

// ---------------------------------------------------------------------------
// Final (R5 rework of the R3 fusion): FIN_R=4 -> 500 blocks (2/CU, 8 waves);
// patient loads issued FIRST (in flight under the med stream); med loop
// unrolled x2 (4 loads in flight); cvec matvec FUSED into the simi GEMM
// f-loop (8 outW loads + 5 acc chains per iteration).
// Measured R4: 44-48 us @ 8.5% occupancy, ~640 cyc/load-iter (serialized).
// ---------------------------------------------------------------------------
constexpr int FIN_R = 4;   // P % FIN_R == 0 -> 500 blocks
__global__ __launch_bounds__(256) void k_final_all(
    const float* __restrict__ e0, const float* __restrict__ e1,
    const float* __restrict__ e2, const float* __restrict__ e3,
    const float* __restrict__ w, const float* __restrict__ outW,
    const float* __restrict__ outb,
    float* __restrict__ out_med, float* __restrict__ out_pat,
    float* __restrict__ simi) {
  int t = threadIdx.x;
  // betas
  float mm0 = w[2] * (1.f / M), mm1 = w[3] * (1.f / M);
  float mmx = fmaxf(mm0, mm1);
  float bm0 = expf(mm0 - mmx), bm1 = expf(mm1 - mmx);
  float msc = 1.f / (bm0 + bm1);
  bm0 *= msc; bm1 *= msc;
  float pm0 = w[0] * (1.f / P), pm1 = w[1] * (1.f / P);
  float pmx = fmaxf(pm0, pm1);
  float bp0 = expf(pm0 - pmx), bp1 = expf(pm1 - pmx);
  float psc = 1.f / (bp0 + bp1);
  bp0 *= psc; bp1 *= psc;
  // ---- patient rows: issue loads FIRST (FIN_R*64 == 256 -> one per thread) --
  int r0 = blockIdx.x * FIN_R;
  int pr = t >> 6, pln = t & 63;
  size_t poff = (size_t)(r0 + pr) * F + (pln << 2);
  float4 pu0 = *(const float4*)(e0 + poff);
  float4 pu1 = *(const float4*)(e1 + poff);
  // ---- med combine + relu col-sum, unrolled x2 (4 loads in flight) ----
  constexpr int MED4 = M * F / 4;   // 9600
  float4 rs = {0.f, 0.f, 0.f, 0.f};
  bool wr_med = (blockIdx.x == 0);
  for (int j = t; j < MED4; j += 512) {
    float4 u0 = ((const float4*)e2)[j], u1 = ((const float4*)e3)[j];
    float4 v0, v1;
    bool second = (j + 256) < MED4;
    if (second) { v0 = ((const float4*)e2)[j + 256]; v1 = ((const float4*)e3)[j + 256]; }
    float4 r = {bm0 * u0.x + bm1 * u1.x, bm0 * u0.y + bm1 * u1.y,
                bm0 * u0.z + bm1 * u1.z, bm0 * u0.w + bm1 * u1.w};
    if (wr_med) ((float4*)out_med)[j] = r;
    rs.x += r.x > 0.f ? r.x : 0.f;
    rs.y += r.y > 0.f ? r.y : 0.f;
    rs.z += r.z > 0.f ? r.z : 0.f;
    rs.w += r.w > 0.f ? r.w : 0.f;
    if (second) {
      float4 r2 = {bm0 * v0.x + bm1 * v1.x, bm0 * v0.y + bm1 * v1.y,
                   bm0 * v0.z + bm1 * v1.z, bm0 * v0.w + bm1 * v1.w};
      if (wr_med) ((float4*)out_med)[j + 256] = r2;
      rs.x += r2.x > 0.f ? r2.x : 0.f;
      rs.y += r2.y > 0.f ? r2.y : 0.f;
      rs.z += r2.z > 0.f ? r2.z : 0.f;
      rs.w += r2.w > 0.f ? r2.w : 0.f;
    }
  }
  // ---- patient combine written to LDS + out_pat (before sv barriers) ----
  __shared__ float psh[FIN_R][F];
  {
    float4 v = {bp0 * pu0.x + bp1 * pu1.x, bp0 * pu0.y + bp1 * pu1.y,
                bp0 * pu0.z + bp1 * pu1.z, bp0 * pu0.w + bp1 * pu1.w};
    *(float4*)(out_pat + poff) = v;
    v.x = v.x > 0.f ? v.x : 0.f; v.y = v.y > 0.f ? v.y : 0.f;
    v.z = v.z > 0.f ? v.z : 0.f; v.w = v.w > 0.f ? v.w : 0.f;
    *(float4*)&psh[pr][pln << 2] = v;
  }
  // ---- sv reduce (barriers also publish psh) ----
  __shared__ float4 sv4[4][64];
  sv4[t >> 6][t & 63] = rs;
  __syncthreads();
  __shared__ float sv[F];
  if (t < 64) {
    float4 a = sv4[0][t], b = sv4[1][t], c = sv4[2][t], d = sv4[3][t];
    sv[t * 4 + 0] = a.x + b.x + c.x + d.x;
    sv[t * 4 + 1] = a.y + b.y + c.y + d.y;
    sv[t * 4 + 2] = a.z + b.z + c.z + d.z;
    sv[t * 4 + 3] = a.w + b.w + c.w + d.w;
  }
  __syncthreads();
  // ---- fused cvec + simi GEMM: 8 outW loads, 5 acc chains per f-step ----
  if (t < M) {
    float acc[FIN_R];
#pragma unroll
    for (int r = 0; r < FIN_R; ++r) acc[r] = 0.f;
    float cv = (float)M * outb[t];
    for (int f = 0; f < F; f += 4) {
      float w0 = outW[(size_t)f * M + t],       w1 = outW[(size_t)(f + 1) * M + t],
            w2 = outW[(size_t)(f + 2) * M + t], w3 = outW[(size_t)(f + 3) * M + t];
      float b0 = outW[(size_t)(F + f) * M + t],     b1 = outW[(size_t)(F + f + 1) * M + t],
            b2 = outW[(size_t)(F + f + 2) * M + t], b3 = outW[(size_t)(F + f + 3) * M + t];
      cv += sv[f] * b0 + sv[f + 1] * b1 + sv[f + 2] * b2 + sv[f + 3] * b3;
#pragma unroll
      for (int r = 0; r < FIN_R; ++r) {
        float4 p4 = *(const float4*)&psh[r][f];
        acc[r] += p4.x * w0 + p4.y * w1 + p4.z * w2 + p4.w * w3;
      }
    }
#pragma unroll
    for (int r = 0; r < FIN_R; ++r)
      simi[(size_t)(r0 + r) * M + t] = (float)M * acc[r] + cv;
  }
}

// ---------------------------------------------------------------------------
extern "C" void kernel_launch(void* const* d_in, const int* in_sizes, int n_in,
                              void* d_out, int out_size, void* d_ws, size_t ws_size,
                              hipStream_t stream) {
  const int*   adj1_rows = (const int*)d_in[0];
  const int*   adj1_cols = (const int*)d_in[1];
  const float* adj1_vals = (const float*)d_in[2];
  const int*   adj2_rows = (const int*)d_in[3];
  const int*   adj2_cols = (const int*)d_in[4];
  const float* adj2_vals = (const float*)d_in[5];
  const int*   g0_src = (const int*)d_in[6];
  const int*   g0_dst = (const int*)d_in[7];
  const int*   g1_src = (const int*)d_in[8];
  const int*   g1_dst = (const int*)d_in[9];
  const int*   g2_src = (const int*)d_in[10];
  const int*   g2_dst = (const int*)d_in[11];
  const int*   g3_src = (const int*)d_in[12];
  const int*   g3_dst = (const int*)d_in[13];
  // d_in[14] = keepRate (unused, == 1)
  const float* pE     = (const float*)d_in[15];
  const float* mE     = (const float*)d_in[16];
  const float* dE     = (const float*)d_in[17];
  const float* gat_W  = (const float*)d_in[18];
  const float* gat_al = (const float*)d_in[19];
  const float* gat_ar = (const float*)d_in[20];
  const float* gat_b  = (const float*)d_in[21];
  const float* sa_W1  = (const float*)d_in[22];
  const float* sa_b1  = (const float*)d_in[23];
  const float* sa_W2  = (const float*)d_in[24];
  const float* out_W  = (const float*)d_in[25];
  const float* out_b  = (const float*)d_in[26];

  // ---- workspace layout: [zeroed (padded counters) | ELL | fp16 | fp32] ----
  int* ip = (int*)d_ws;
  int* cur1 = ip; ip += (size_t)N1 * CPAD;
  int* cur2 = ip; ip += (size_t)N2 * CPAD;
  int* cu0  = ip; ip += (size_t)P * CPAD;
  int* cu1  = ip; ip += (size_t)P * CPAD;
  int* cu2  = ip; ip += (size_t)M * CPAD;
  int* cu3  = ip; ip += (size_t)M * CPAD;
  int* ovf_n = ip; ip += 6;
  float* wbuf = (float*)ip; ip += 4;
  size_t memset_bytes = (size_t)((char*)ip - (char*)d_ws);

  uintptr_t up = ((uintptr_t)ip + 15) & ~(uintptr_t)15;
  int4* ovf = (int4*)up;                       // 6 * OVF_CAP
  uint2* ell1 = (uint2*)(ovf + 6 * OVF_CAP);   // N1 * CAP_A
  uint2* ell2 = ell1 + (size_t)N1 * CAP_A;     // N2 * CAP_A
  unsigned* eg0 = (unsigned*)(ell2 + (size_t)N2 * CAP_A);
  unsigned* eg1 = eg0 + (size_t)P * CAP_G;
  unsigned* eg2 = eg1 + (size_t)P * CAP_G;
  unsigned* eg3 = eg2 + (size_t)M * CAP_G;
  // fp16 region (16B-aligned by construction)
  __half* hp = (__half*)(eg3 + (size_t)M * CAP_G);
  __half* pEh   = hp; hp += (size_t)P * F;
  __half* mEh   = hp; hp += (size_t)M * F;
  __half* dEh   = hp; hp += (size_t)DG * F;
  __half* lat1h = hp; hp += (size_t)N1 * F;
  __half* lat2h = hp; hp += (size_t)N2 * F;
  __half* f0h   = hp; hp += (size_t)P * F;
  __half* f1h   = hp; hp += (size_t)P * F;
  __half* f2h   = hp; hp += (size_t)M * F;
  __half* f3h   = hp; hp += (size_t)M * F;
  float* fp = (float*)hp;
  float* lat1f = fp; fp += (size_t)N1 * F;
  float* lat2f = fp; fp += (size_t)N2 * F;
  float* acc1  = fp; fp += (size_t)N1 * F;
  float* acc2  = fp; fp += (size_t)N2 * F;
  float* el    = fp; fp += (size_t)(2 * P + 2 * M) * H;
  float* er    = fp; fp += (size_t)(2 * P + 2 * M) * H;
  float* e0b   = fp; fp += (size_t)P * F;
  float* e1b   = fp; fp += (size_t)P * F;
  float* e2b   = fp; fp += (size_t)M * F;
  float* e3b   = fp; fp += (size_t)M * F;

  // ---- output layout: (simi_pm, d_gcn, med, m_gcn, patient) ----
  float* out_simi = (float*)d_out;               // P*M
  float* out_dgcn = out_simi + (size_t)P * M;    // DG*F
  float* out_med  = out_dgcn + (size_t)DG * F;   // M*F
  float* out_mgcn = out_med  + (size_t)M * F;    // M*F
  float* out_pat  = out_mgcn + (size_t)M * F;    // P*F

  // ---- zero padded counters (~540 KB) ----
  hipMemsetAsync(d_ws, 0, memset_bytes, stream);

  // ---- ELL build + fused fp16 embed cast: ONE dispatch ----
  int eb = ((HOE + 3) / 4 + 255) / 256;
  k_build<<<eb, 256, 0, stream>>>(adj1_rows, adj1_cols, adj1_vals,
                                  adj2_rows, adj2_cols, adj2_vals,
                                  g0_dst, g0_src, g1_dst, g1_src,
                                  g2_dst, g2_src, g3_dst, g3_src,
                                  cur1, ell1, cur2, ell2,
                                  cu0, eg0, cu1, eg1, cu2, eg2, cu3, eg3,
                                  ovf_n, ovf,
                                  pE, mE, dE, pEh, mEh, dEh);

  // ---- GNN: 2 layers, 2 waves per row (edge-parity split) ----
  int sb = (N1 + N2) / 2;
  k_spmm<1><<<sb, 256, 0, stream>>>(cur1, ell1, cur2, ell2, ovf_n, ovf,
                                    pEh, mEh, dEh, lat1f, lat2f, lat1h, lat2h,
                                    acc1, acc2, out_mgcn, out_dgcn);
  k_spmm<2><<<sb, 256, 0, stream>>>(cur1, ell1, cur2, ell2, ovf_n, ovf,
                                    pEh, mEh, dEh, lat1f, lat2f, lat1h, lat2h,
                                    acc1, acc2, out_mgcn, out_dgcn);

  // ---- 4 GATs: scalar feature GEMM + 2-wave-split aggregation ----
  k_gat_feat_all<<<FEAT_BLOCKS, 256, 0, stream>>>(acc1, acc2, gat_W, gat_al, gat_ar,
                                                  f0h, f1h, f2h, f3h, el, er);
  int ab = (2 * P + 2 * M) / 2;   // 4300 groups * 128 threads / 256
  k_gat_agg_all<<<ab, 256, 0, stream>>>(cu0, eg0, cu1, eg1, cu2, eg2, cu3, eg3,
                                        ovf_n, ovf, el, er, f0h, f1h, f2h, f3h, gat_b,
                                        e0b, e1b, e2b, e3b);

  // ---- semantic attention weights ----
  k_sem_w_all<<<SEM_BLOCKS, 128, 0, stream>>>(e0b, e1b, e2b, e3b, sa_W1, sa_b1, sa_W2, wbuf);

  // ---- final: med+cvec+patient+simi fused (FIN_R=4, 500 blocks) ----
  k_final_all<<<P / FIN_R, 256, 0, stream>>>(e0b, e1b, e2b, e3b, wbuf, out_W, out_b,
                                             out_med, out_pat, out_simi);
}